// Round 14
// baseline (2138.510 us; speedup 1.0000x reference)
//
#include <hip/hip_runtime.h>
#include <hip/hip_bf16.h>
#include <cstddef>

#define NB 32      // batch
#define NP 196     // pixels
#define NE 2048    // encoder dim
#define ND 512     // decoder/att/emb dim
#define NV 32000   // vocab
#define NL 21
#define NT 20      // decode steps

typedef __attribute__((ext_vector_type(8))) short short8;   // 8 bf16 (4 VGPRs)
typedef __attribute__((ext_vector_type(4))) float f32x4;

__device__ __forceinline__ unsigned short f2b(float f) {
    __hip_bfloat16 h = __float2bfloat16(f);      // RNE
    return *reinterpret_cast<unsigned short*>(&h);
}
__device__ __forceinline__ float b2f_lo(unsigned int u) {
    union { unsigned int i; float f; } v; v.i = u << 16; return v.f;
}
__device__ __forceinline__ float b2f_hi(unsigned int u) {
    union { unsigned int i; float f; } v; v.i = u & 0xffff0000u; return v.f;
}

// ---------------- setup ----------------

__global__ void k_sort(const int* __restrict__ lens, int* __restrict__ sind, int* __restrict__ dlens,
                       int* __restrict__ rowmap, int* __restrict__ mpad)
{
    int i = threadIdx.x;
    if (i < NB) {
        int li = lens[i];
        int r = 0;
        for (int j = 0; j < NB; ++j) {
            int lj = lens[j];
            if (lj > li || (lj == li && j < i)) ++r;
        }
        sind[r] = i;
        dlens[r] = li - 1;
    }
    __syncthreads();
    if (i == 0) {
        int c = 0;
        for (int t = 0; t < NT; ++t)
            for (int b = 0; b < NB; ++b)
                if (t < dlens[b]) rowmap[c++] = t * NB + b;
        int pad = (c + 63) & ~63;
        for (int r = c; r < pad; ++r) rowmap[r] = -1;
        mpad[0] = pad;
    }
}

__global__ __launch_bounds__(256) void k_mean(const float* __restrict__ enc, const int* __restrict__ sind,
                                              float* __restrict__ mean_enc)
{
    int b = blockIdx.y;
    int k = blockIdx.x * 256 + threadIdx.x;
    const float* e = enc + (size_t)sind[b] * NP * NE + k;
    float s0 = 0.f, s1 = 0.f, s2 = 0.f, s3 = 0.f;
    for (int p = 0; p < NP; p += 4) {
        s0 += e[(size_t)(p + 0) * NE];
        s1 += e[(size_t)(p + 1) * NE];
        s2 += e[(size_t)(p + 2) * NE];
        s3 += e[(size_t)(p + 3) * NE];
    }
    mean_enc[(size_t)b * NE + k] = (s0 + s1 + s2 + s3) * (1.0f / NP);
}

__global__ __launch_bounds__(256) void k_zero(const int* __restrict__ dlens, float* __restrict__ out)
{
    int b = blockIdx.x / NT, t = blockIdx.x % NT;
    if (t < dlens[b]) return;
    float4 z = {0.f, 0.f, 0.f, 0.f};
    float4* row = (float4*)(out + ((size_t)b * NT + t) * NV);
    for (int i = threadIdx.x; i < NV / 4; i += 256) row[i] = z;
}

// convert W_da (512x512) | W_fb (2048x512) -> wdfB [1024 rows? no: 512+2048]... rows: n<512 W_da else W_fb
// NOTE: attg has 2560 outputs (512 att2 + 2048 gate) -> wdfB is [2560][512]
__global__ __launch_bounds__(256) void k_conv_df(
    const float* __restrict__ W_da, const float* __restrict__ W_fb,
    unsigned short* __restrict__ wdfB)
{
    int idx = (blockIdx.x * 256 + threadIdx.x) * 8;   // over 2560*512 = 1310720 elems -> 640 blocks
    if (idx >= 2560 * 512) return;
    int n = idx >> 9, k = idx & 511;
    const float* src = (n < 512) ? (W_da + (size_t)n * 512 + k)
                                 : (W_fb + (size_t)(n - 512) * 512 + k);
    float4 a = *reinterpret_cast<const float4*>(src);
    float4 b = *reinterpret_cast<const float4*>(src + 4);
    uint4 o;
    o.x = f2b(a.x) | ((unsigned)f2b(a.y) << 16);
    o.y = f2b(a.z) | ((unsigned)f2b(a.w) << 16);
    o.z = f2b(b.x) | ((unsigned)f2b(b.y) << 16);
    o.w = f2b(b.z) | ((unsigned)f2b(b.w) << 16);
    *reinterpret_cast<uint4*>(wdfB + idx) = o;
}

// fuse W_ih (2048x2560) + W_hh (2048x512) -> wxhB [2048][3072] contiguous rows
__global__ __launch_bounds__(256) void k_conv_xh(
    const float* __restrict__ W_ih, const float* __restrict__ W_hh,
    unsigned short* __restrict__ wxhB)
{
    int idx = (blockIdx.x * 256 + threadIdx.x) * 8;   // over 2048*3072 = 6291456 -> 3072 blocks
    if (idx >= 2048 * 3072) return;
    int n = idx / 3072, kk = idx % 3072;
    const float* src = (kk < 2560) ? (W_ih + (size_t)n * 2560 + kk)
                                   : (W_hh + (size_t)n * 512 + (kk - 2560));
    float4 a = *reinterpret_cast<const float4*>(src);
    float4 b = *reinterpret_cast<const float4*>(src + 4);
    uint4 o;
    o.x = f2b(a.x) | ((unsigned)f2b(a.y) << 16);
    o.y = f2b(a.z) | ((unsigned)f2b(a.w) << 16);
    o.z = f2b(b.x) | ((unsigned)f2b(b.y) << 16);
    o.w = f2b(b.z) | ((unsigned)f2b(b.w) << 16);
    *reinterpret_cast<uint4*>(wxhB + idx) = o;
}

// ---------------- h0/c0 skinny GEMM, split-K=8 (grid 16 x 8) -> partials in spart ----------------
__global__ __launch_bounds__(256) void gemm_skinny_split(
    const float* __restrict__ A0, const float* __restrict__ W0a, const float* __restrict__ W0b,
    float* __restrict__ spart)
{
    __shared__ float As[32][32];
    __shared__ float Ws[64][33];
    int n0 = blockIdx.x * 64;
    int ks = blockIdx.y;
    int tid = threadIdx.x;
    int lb = tid / 8, lkq = tid % 8;
    int b4 = (tid / 32) * 4, nl = (tid % 32) * 2;
    float acc[4][2] = {};
    for (int kt = ks * 256; kt < ks * 256 + 256; kt += 32) {
        float4 a4 = *reinterpret_cast<const float4*>(A0 + (size_t)lb * NE + kt + lkq * 4);
        As[lkq * 4 + 0][lb] = a4.x; As[lkq * 4 + 1][lb] = a4.y;
        As[lkq * 4 + 2][lb] = a4.z; As[lkq * 4 + 3][lb] = a4.w;
        #pragma unroll
        for (int r = 0; r < 2; ++r) {
            int s = tid + r * 256;
            int n_l = s / 8, kq = s % 8;
            int ng = n0 + n_l;
            const float* wrow = (ng < 512) ? (W0a + (size_t)ng * NE)
                                           : (W0b + (size_t)(ng - 512) * NE);
            float4 w4 = *reinterpret_cast<const float4*>(wrow + kt + kq * 4);
            Ws[n_l][kq * 4 + 0] = w4.x; Ws[n_l][kq * 4 + 1] = w4.y;
            Ws[n_l][kq * 4 + 2] = w4.z; Ws[n_l][kq * 4 + 3] = w4.w;
        }
        __syncthreads();
        #pragma unroll
        for (int k = 0; k < 32; ++k) {
            float4 av = *reinterpret_cast<const float4*>(&As[k][b4]);
            float w0 = Ws[nl][k], w1 = Ws[nl + 1][k];
            acc[0][0] += av.x * w0; acc[0][1] += av.x * w1;
            acc[1][0] += av.y * w0; acc[1][1] += av.y * w1;
            acc[2][0] += av.z * w0; acc[2][1] += av.z * w1;
            acc[3][0] += av.w * w0; acc[3][1] += av.w * w1;
        }
        __syncthreads();
    }
    float* Cp = spart + (size_t)ks * NB * 1024;
    #pragma unroll
    for (int j = 0; j < 2; ++j)
        #pragma unroll
        for (int i = 0; i < 4; ++i)
            Cp[(size_t)(b4 + i) * 1024 + n0 + nl + j] = acc[i][j];
}

// combine partials + bias -> hc; seed xh h-part (grid NB)
__global__ __launch_bounds__(256) void k_hc0(
    const float* __restrict__ spart, const float* __restrict__ ba, const float* __restrict__ bb,
    float* __restrict__ hc, float* __restrict__ xh)
{
    int b = blockIdx.x;
    for (int ng = threadIdx.x; ng < 1024; ng += 256) {
        float s = (ng < 512) ? ba[ng] : bb[ng - 512];
        #pragma unroll
        for (int ks = 0; ks < 8; ++ks)
            s += spart[(size_t)ks * NB * 1024 + (size_t)b * 1024 + ng];
        hc[(size_t)b * 1024 + ng] = s;
        if (ng < 512) xh[(size_t)b * 3072 + 2560 + ng] = s;
    }
}

// ---------------- att1 GEMM (bf16 MFMA), XCD-swizzled ----------------
__global__ __launch_bounds__(256) void gemm_att1_mfma(
    const float* __restrict__ enc, const float* __restrict__ W_ea,
    const float* __restrict__ bias, unsigned short* __restrict__ att1B,
    const int* __restrict__ sind)
{
    int fid = blockIdx.x;
    int c = fid & 7, x = (fid >> 3) & 7, pg = fid >> 6;
    int p = pg * 8 + c;
    if (p >= 98) return;
    int bm0 = p * 64, bn0 = x * 64;
    __shared__ unsigned short As[64][40];
    __shared__ unsigned short Bs[64][40];
    int tid = threadIdx.x;
    int w = tid >> 6, lane = tid & 63;
    int srow = tid >> 2, schunk = (tid & 3) * 8;
    int mg = bm0 + srow;
    int bidx = mg / NP, pp = mg - bidx * NP;
    const float* arow = enc + ((size_t)sind[bidx] * NP + pp) * NE + schunk;
    const float* brow = W_ea + (size_t)(bn0 + srow) * NE + schunk;
    int frow = lane & 15, fk = (lane >> 4) * 8;
    f32x4 acc[4] = {};
    for (int kt = 0; kt < NE; kt += 32) {
        float4 a0 = *reinterpret_cast<const float4*>(arow + kt);
        float4 a1 = *reinterpret_cast<const float4*>(arow + kt + 4);
        float4 b0 = *reinterpret_cast<const float4*>(brow + kt);
        float4 b1 = *reinterpret_cast<const float4*>(brow + kt + 4);
        uint4 av, bv;
        av.x = f2b(a0.x) | ((unsigned)f2b(a0.y) << 16);
        av.y = f2b(a0.z) | ((unsigned)f2b(a0.w) << 16);
        av.z = f2b(a1.x) | ((unsigned)f2b(a1.y) << 16);
        av.w = f2b(a1.z) | ((unsigned)f2b(a1.w) << 16);
        bv.x = f2b(b0.x) | ((unsigned)f2b(b0.y) << 16);
        bv.y = f2b(b0.z) | ((unsigned)f2b(b0.w) << 16);
        bv.z = f2b(b1.x) | ((unsigned)f2b(b1.y) << 16);
        bv.w = f2b(b1.z) | ((unsigned)f2b(b1.w) << 16);
        *reinterpret_cast<uint4*>(&As[srow][schunk]) = av;
        *reinterpret_cast<uint4*>(&Bs[srow][schunk]) = bv;
        __syncthreads();
        short8 af = *reinterpret_cast<const short8*>(&As[w * 16 + frow][fk]);
        #pragma unroll
        for (int n = 0; n < 4; ++n) {
            short8 bf = *reinterpret_cast<const short8*>(&Bs[n * 16 + frow][fk]);
            acc[n] = __builtin_amdgcn_mfma_f32_16x16x32_bf16(af, bf, acc[n], 0, 0, 0);
        }
        __syncthreads();
    }
    int crow = bm0 + w * 16 + (lane >> 4) * 4;
    int ccol0 = lane & 15;
    #pragma unroll
    for (int n = 0; n < 4; ++n) {
        int col = bn0 + n * 16 + ccol0;
        float bb2 = bias[col];
        #pragma unroll
        for (int i = 0; i < 4; ++i)
            att1B[(size_t)(crow + i) * ND + col] = f2b(acc[n][i] + bb2);
    }
}

// ---------------- preds GEMM (bf16 MFMA), XCD-swizzled ----------------
__global__ __launch_bounds__(256) void gemm_preds_mfma(
    const unsigned short* __restrict__ hseqB, const float* __restrict__ W_fc,
    const float* __restrict__ bias, float* __restrict__ out,
    const int* __restrict__ rowmap, const int* __restrict__ mpad)
{
    int fid = blockIdx.x;
    int c = fid & 7;
    int rem = fid >> 3;
    int m = rem % 10, g = rem / 10;
    int n = g * 8 + c;
    if (n >= 250) return;
    int bm0 = m * 64;
    if (bm0 >= mpad[0]) return;
    int bn0 = n * 128;
    __shared__ unsigned short As[64][40];
    __shared__ unsigned short Bs[128][40];
    int tid = threadIdx.x;
    int w = tid >> 6, lane = tid & 63;
    int srow = tid >> 2, schunk = (tid & 3) * 8;
    int rid = rowmap[bm0 + srow];
    const unsigned short* aptr = hseqB + (size_t)(rid < 0 ? 0 : rid) * ND + schunk;
    const float* bptr0 = W_fc + (size_t)(bn0 + srow) * ND + schunk;
    const float* bptr1 = W_fc + (size_t)(bn0 + 64 + srow) * ND + schunk;
    int frow = lane & 15, fk = (lane >> 4) * 8;
    f32x4 acc[8] = {};
    for (int kt = 0; kt < ND; kt += 32) {
        uint4 av = *reinterpret_cast<const uint4*>(aptr + kt);
        float4 c0 = *reinterpret_cast<const float4*>(bptr0 + kt);
        float4 c1 = *reinterpret_cast<const float4*>(bptr0 + kt + 4);
        float4 d0 = *reinterpret_cast<const float4*>(bptr1 + kt);
        float4 d1 = *reinterpret_cast<const float4*>(bptr1 + kt + 4);
        uint4 bv0, bv1;
        bv0.x = f2b(c0.x) | ((unsigned)f2b(c0.y) << 16);
        bv0.y = f2b(c0.z) | ((unsigned)f2b(c0.w) << 16);
        bv0.z = f2b(c1.x) | ((unsigned)f2b(c1.y) << 16);
        bv0.w = f2b(c1.z) | ((unsigned)f2b(c1.w) << 16);
        bv1.x = f2b(d0.x) | ((unsigned)f2b(d0.y) << 16);
        bv1.y = f2b(d0.z) | ((unsigned)f2b(d0.w) << 16);
        bv1.z = f2b(d1.x) | ((unsigned)f2b(d1.y) << 16);
        bv1.w = f2b(d1.z) | ((unsigned)f2b(d1.w) << 16);
        *reinterpret_cast<uint4*>(&As[srow][schunk]) = av;
        *reinterpret_cast<uint4*>(&Bs[srow][schunk]) = bv0;
        *reinterpret_cast<uint4*>(&Bs[64 + srow][schunk]) = bv1;
        __syncthreads();
        short8 af = *reinterpret_cast<const short8*>(&As[w * 16 + frow][fk]);
        #pragma unroll
        for (int nn = 0; nn < 8; ++nn) {
            short8 bf = *reinterpret_cast<const short8*>(&Bs[nn * 16 + frow][fk]);
            acc[nn] = __builtin_amdgcn_mfma_f32_16x16x32_bf16(af, bf, acc[nn], 0, 0, 0);
        }
        __syncthreads();
    }
    int rl0 = w * 16 + (lane >> 4) * 4;
    int ccol0 = lane & 15;
    #pragma unroll
    for (int i = 0; i < 4; ++i) {
        int rm = rowmap[bm0 + rl0 + i];
        if (rm < 0) continue;
        int t = rm / NB, b = rm % NB;
        float* orow = out + ((size_t)b * NT + t) * NV;
        #pragma unroll
        for (int nn = 0; nn < 8; ++nn) {
            int col = bn0 + nn * 16 + ccol0;
            orow[col] = acc[nn][i] + bias[col];
        }
    }
}

// ---------------- k_attg: attg[32][2560] = h @ wdfB^T + [b_da;b_fb] (40 blocks, bf16 W) ----------------
__global__ __launch_bounds__(256) void k_attg(
    const float* __restrict__ hc, const unsigned short* __restrict__ wdfB,
    const float* __restrict__ b_da, const float* __restrict__ b_fb, float* __restrict__ attg)
{
    __shared__ float As[32][32];
    __shared__ float Ws[64][33];
    int n0 = blockIdx.x * 64;
    int tid = threadIdx.x;
    int lb = tid / 8, lkq = tid % 8;
    int wn = tid >> 2, wk = (tid & 3) * 8;
    int b4 = (tid / 32) * 4, nl = (tid % 32) * 2;
    float acc[4][2] = {};
    for (int kt = 0; kt < 512; kt += 32) {
        float4 a4 = *reinterpret_cast<const float4*>(hc + (size_t)lb * 1024 + kt + lkq * 4);
        As[lkq * 4 + 0][lb] = a4.x; As[lkq * 4 + 1][lb] = a4.y;
        As[lkq * 4 + 2][lb] = a4.z; As[lkq * 4 + 3][lb] = a4.w;
        uint4 u = *reinterpret_cast<const uint4*>(wdfB + (size_t)(n0 + wn) * 512 + kt + wk);
        Ws[wn][wk + 0] = b2f_lo(u.x); Ws[wn][wk + 1] = b2f_hi(u.x);
        Ws[wn][wk + 2] = b2f_lo(u.y); Ws[wn][wk + 3] = b2f_hi(u.y);
        Ws[wn][wk + 4] = b2f_lo(u.z); Ws[wn][wk + 5] = b2f_hi(u.z);
        Ws[wn][wk + 6] = b2f_lo(u.w); Ws[wn][wk + 7] = b2f_hi(u.w);
        __syncthreads();
        #pragma unroll
        for (int k = 0; k < 32; ++k) {
            float4 av = *reinterpret_cast<const float4*>(&As[k][b4]);
            float w0 = Ws[nl][k], w1 = Ws[nl + 1][k];
            acc[0][0] += av.x * w0; acc[0][1] += av.x * w1;
            acc[1][0] += av.y * w0; acc[1][1] += av.y * w1;
            acc[2][0] += av.z * w0; acc[2][1] += av.z * w1;
            acc[3][0] += av.w * w0; acc[3][1] += av.w * w1;
        }
        __syncthreads();
    }
    #pragma unroll
    for (int j = 0; j < 2; ++j) {
        int ng = n0 + nl + j;
        float bias = (ng < 512) ? b_da[ng] : b_fb[ng - 512];
        #pragma unroll
        for (int i = 0; i < 4; ++i)
            attg[(size_t)(b4 + i) * 2560 + ng] = acc[i][j] + bias;
    }
}

// ---------------- k_eawe: wave-per-p e scores + softmax + awe + gate + xh (grid 8 x 32) ----------------
__global__ __launch_bounds__(256) void k_eawe(
    const float* __restrict__ enc, const int* __restrict__ sind, const int* __restrict__ dlens,
    const int* __restrict__ caps, const float* __restrict__ emb_W,
    const unsigned short* __restrict__ att1B, const float* __restrict__ attg,
    const float* __restrict__ w_fa, const float* __restrict__ b_fa,
    float* __restrict__ xh, float* __restrict__ out_alpha, int t)
{
    __shared__ float att2s[512];
    __shared__ float wfas[512];
    __shared__ float es[256];
    __shared__ float red[256];
    int kc = blockIdx.x, b = blockIdx.y, tid = threadIdx.x;
    const float* ag = attg + (size_t)b * 2560;
    att2s[tid] = ag[tid]; att2s[256 + tid] = ag[256 + tid];
    wfas[tid] = w_fa[tid]; wfas[256 + tid] = w_fa[256 + tid];
    __syncthreads();
    // e scores: wave-per-p, 64-lane dot (8 bf16 per lane), shuffle reduce
    int w = tid >> 6, lane = tid & 63;
    float bfa = b_fa[0];
    int d0 = lane * 8;
    const unsigned short* a1 = att1B + (size_t)b * NP * ND;
    for (int i = 0; i < 49; ++i) {
        int p = w + 4 * i;
        uint4 u = *reinterpret_cast<const uint4*>(a1 + (size_t)p * ND + d0);
        float s = fmaxf(b2f_lo(u.x) + att2s[d0 + 0], 0.f) * wfas[d0 + 0]
                + fmaxf(b2f_hi(u.x) + att2s[d0 + 1], 0.f) * wfas[d0 + 1]
                + fmaxf(b2f_lo(u.y) + att2s[d0 + 2], 0.f) * wfas[d0 + 2]
                + fmaxf(b2f_hi(u.y) + att2s[d0 + 3], 0.f) * wfas[d0 + 3]
                + fmaxf(b2f_lo(u.z) + att2s[d0 + 4], 0.f) * wfas[d0 + 4]
                + fmaxf(b2f_hi(u.z) + att2s[d0 + 5], 0.f) * wfas[d0 + 5]
                + fmaxf(b2f_lo(u.w) + att2s[d0 + 6], 0.f) * wfas[d0 + 6]
                + fmaxf(b2f_hi(u.w) + att2s[d0 + 7], 0.f) * wfas[d0 + 7];
        for (int off = 32; off > 0; off >>= 1) s += __shfl_down(s, off);
        if (lane == 0) es[p] = s + bfa;
    }
    __syncthreads();
    // softmax over es[0..195]
    float ev = (tid < NP) ? es[tid] : -1e30f;
    red[tid] = ev; __syncthreads();
    for (int s2 = 128; s2 > 0; s2 >>= 1) { if (tid < s2) red[tid] = fmaxf(red[tid], red[tid + s2]); __syncthreads(); }
    float m = red[0]; __syncthreads();
    float xe = (tid < NP) ? expf(ev - m) : 0.f;
    red[tid] = xe; __syncthreads();
    for (int s2 = 128; s2 > 0; s2 >>= 1) { if (tid < s2) red[tid] += red[tid + s2]; __syncthreads(); }
    float inv = 1.0f / red[0];
    __syncthreads();
    es[tid] = xe * inv;
    __syncthreads();
    // awe + gate for this block's 256 k-columns
    int k = kc * 256 + tid;
    const float* ec = enc + (size_t)sind[b] * NP * NE + k;
    float s0 = 0.f, s1 = 0.f, s2v = 0.f, s3 = 0.f;
    #pragma unroll 4
    for (int p = 0; p < NP; p += 4) {
        s0 += es[p + 0] * ec[(size_t)(p + 0) * NE];
        s1 += es[p + 1] * ec[(size_t)(p + 1) * NE];
        s2v += es[p + 2] * ec[(size_t)(p + 2) * NE];
        s3 += es[p + 3] * ec[(size_t)(p + 3) * NE];
    }
    float awe = (s0 + s1) + (s2v + s3);
    float gp = ag[512 + k];                     // includes b_fb
    float gate = 1.f / (1.f + expf(-gp));
    xh[(size_t)b * 3072 + 512 + k] = gate * awe;
    if (kc == 0) {
        bool live = (t < dlens[b]);
        if (tid < NP) out_alpha[((size_t)b * NT + t) * NP + tid] = live ? es[tid] : 0.f;
        const float* er = emb_W + (size_t)caps[sind[b] * NL + t] * ND;
        xh[(size_t)b * 3072 + tid] = er[tid];
        xh[(size_t)b * 3072 + 256 + tid] = er[256 + tid];
    }
}

// ---------------- k_gates: gates GEMM partials (128 blocks: 32 ntiles x 4 ksplit, bf16 W) ----------------
__global__ __launch_bounds__(256) void k_gates(
    const float* __restrict__ xh, const unsigned short* __restrict__ wxhB,
    float* __restrict__ gpart)
{
    __shared__ float smem[3200];
    int blk = blockIdx.x, tid = threadIdx.x;
    int nt = blk & 31, ks = blk >> 5;
    float* As = smem;
    float (*Ws)[33] = (float(*)[33])(smem + 1024);
    int n0 = nt * 64;
    int lb = tid / 8, lkq = tid % 8;
    int wn = tid >> 2, wk = (tid & 3) * 8;
    int b4 = (tid / 32) * 4, nl = (tid % 32) * 2;
    float acc[4][2] = {};
    for (int kt = ks * 768; kt < ks * 768 + 768; kt += 32) {
        float4 a4 = *reinterpret_cast<const float4*>(xh + (size_t)lb * 3072 + kt + lkq * 4);
        As[(lkq * 4 + 0) * 32 + lb] = a4.x; As[(lkq * 4 + 1) * 32 + lb] = a4.y;
        As[(lkq * 4 + 2) * 32 + lb] = a4.z; As[(lkq * 4 + 3) * 32 + lb] = a4.w;
        uint4 u = *reinterpret_cast<const uint4*>(wxhB + (size_t)(n0 + wn) * 3072 + kt + wk);
        Ws[wn][wk + 0] = b2f_lo(u.x); Ws[wn][wk + 1] = b2f_hi(u.x);
        Ws[wn][wk + 2] = b2f_lo(u.y); Ws[wn][wk + 3] = b2f_hi(u.y);
        Ws[wn][wk + 4] = b2f_lo(u.z); Ws[wn][wk + 5] = b2f_hi(u.z);
        Ws[wn][wk + 6] = b2f_lo(u.w); Ws[wn][wk + 7] = b2f_hi(u.w);
        __syncthreads();
        #pragma unroll
        for (int k = 0; k < 32; ++k) {
            float4 av = *reinterpret_cast<const float4*>(&As[k * 32 + b4]);
            float w0 = Ws[nl][k], w1 = Ws[nl + 1][k];
            acc[0][0] += av.x * w0; acc[0][1] += av.x * w1;
            acc[1][0] += av.y * w0; acc[1][1] += av.y * w1;
            acc[2][0] += av.z * w0; acc[2][1] += av.z * w1;
            acc[3][0] += av.w * w0; acc[3][1] += av.w * w1;
        }
        __syncthreads();
    }
    float* Cp = gpart + (size_t)ks * NB * 2048;
    #pragma unroll
    for (int j = 0; j < 2; ++j)
        #pragma unroll
        for (int i = 0; i < 4; ++i)
            Cp[(size_t)(b4 + i) * 2048 + n0 + nl + j] = acc[i][j];
}

// ---------------- k_cell: reduce partials + LSTM cell; hseq stored bf16 ----------------
__global__ __launch_bounds__(256) void k_cell(
    const float* __restrict__ gpart, const int* __restrict__ dlens,
    const float* __restrict__ b_ih, const float* __restrict__ b_hh,
    float* __restrict__ hc, unsigned short* __restrict__ hseqB, float* __restrict__ xh, int t)
{
    int b = blockIdx.x;
    for (int d = threadIdx.x; d < ND; d += 256) {
        float g0 = b_ih[d] + b_hh[d];
        float g1 = b_ih[512 + d] + b_hh[512 + d];
        float g2 = b_ih[1024 + d] + b_hh[1024 + d];
        float g3 = b_ih[1536 + d] + b_hh[1536 + d];
        #pragma unroll
        for (int ks = 0; ks < 4; ++ks) {
            const float* gp = gpart + ((size_t)ks * NB + b) * 2048;
            g0 += gp[d]; g1 += gp[512 + d]; g2 += gp[1024 + d]; g3 += gp[1536 + d];
        }
        float ig = 1.f / (1.f + expf(-g0));
        float fg = 1.f / (1.f + expf(-g1));
        float gt = tanhf(g2);
        float og = 1.f / (1.f + expf(-g3));
        float c_old = hc[(size_t)b * 1024 + 512 + d];
        float c_new = fg * c_old + ig * gt;
        float h_new = og * tanhf(c_new);
        hseqB[((size_t)t * NB + b) * ND + d] = f2b(h_new);
        if (t < dlens[b]) {
            hc[(size_t)b * 1024 + d] = h_new;
            hc[(size_t)b * 1024 + 512 + d] = c_new;
            xh[(size_t)b * 3072 + 2560 + d] = h_new;
        }
    }
}

// ---------------- launcher ----------------
extern "C" void kernel_launch(void* const* d_in, const int* in_sizes, int n_in,
                              void* d_out, int out_size, void* d_ws, size_t ws_size,
                              hipStream_t stream)
{
    const float* enc   = (const float*)d_in[0];
    const int*   caps  = (const int*)d_in[1];
    const int*   clens = (const int*)d_in[2];
    const float* emb_W = (const float*)d_in[3];
    const float* W_ea  = (const float*)d_in[4];
    const float* b_ea  = (const float*)d_in[5];
    const float* W_da  = (const float*)d_in[6];
    const float* b_da  = (const float*)d_in[7];
    const float* w_fa  = (const float*)d_in[8];
    const float* b_fa  = (const float*)d_in[9];
    const float* W_ih  = (const float*)d_in[10];
    const float* b_ih  = (const float*)d_in[11];
    const float* W_hh  = (const float*)d_in[12];
    const float* b_hh  = (const float*)d_in[13];
    const float* W_h0  = (const float*)d_in[14];
    const float* b_h0  = (const float*)d_in[15];
    const float* W_c0  = (const float*)d_in[16];
    const float* b_c0  = (const float*)d_in[17];
    const float* W_fb  = (const float*)d_in[18];
    const float* b_fb  = (const float*)d_in[19];
    const float* W_fc  = (const float*)d_in[20];
    const float* b_fc  = (const float*)d_in[21];

    float* out = (float*)d_out;
    float* out_alpha = out + (size_t)NB * NT * NV;

    int* iws    = (int*)d_ws;
    int* sind   = iws;
    int* dlens  = iws + 32;
    int* rowmap = iws + 64;
    int* mpad   = iws + 704;
    float* base = (float*)d_ws + 1024;
    float* mean_enc = base;                         // 65536
    float* hc    = mean_enc + NB * NE;              // 32768
    float* attg  = hc + NB * 1024;                  // 81920
    float* xh    = attg + NB * 2560;                // 98304
    float* gpart = xh + NB * 3072;                  // 262144 (spart at setup)
    unsigned short* att1B = (unsigned short*)(gpart + 262144);          // 6272*512 bf16
    unsigned short* hseqB = att1B + (size_t)NB * NP * ND;               // 640*512 bf16
    unsigned short* wdfB  = hseqB + (size_t)NT * NB * ND;               // 2560*512 bf16
    unsigned short* wxhB  = wdfB + (size_t)2560 * 512;                  // 2048*3072 bf16

    k_sort<<<1, 64, 0, stream>>>(clens, sind, dlens, rowmap, mpad);
    k_zero<<<NB * NT, 256, 0, stream>>>(dlens, out);
    k_conv_df<<<dim3(640), 256, 0, stream>>>(W_da, W_fb, wdfB);
    k_conv_xh<<<dim3(3072), 256, 0, stream>>>(W_ih, W_hh, wxhB);
    k_mean<<<dim3(NE / 256, NB), 256, 0, stream>>>(enc, sind, mean_enc);
    gemm_skinny_split<<<dim3(16, 8), 256, 0, stream>>>(mean_enc, W_h0, W_c0, gpart);
    k_hc0<<<dim3(NB), 256, 0, stream>>>(gpart, b_h0, b_c0, hc, xh);
    gemm_att1_mfma<<<dim3(832), 256, 0, stream>>>(enc, W_ea, b_ea, att1B, sind);

    for (int t = 0; t < NT; ++t) {
        k_attg<<<dim3(40), 256, 0, stream>>>(hc, wdfB, b_da, b_fb, attg);
        k_eawe<<<dim3(8, NB), 256, 0, stream>>>(enc, sind, dlens, caps, emb_W,
                                                att1B, attg, w_fa, b_fa,
                                                xh, out_alpha, t);
        k_gates<<<dim3(128), 256, 0, stream>>>(xh, wxhB, gpart);
        k_cell<<<dim3(NB), 256, 0, stream>>>(gpart, dlens, b_ih, b_hh, hc, hseqB, xh, t);
    }

    gemm_preds_mfma<<<dim3(2560), 256, 0, stream>>>(hseqB, W_fc, b_fc, out, rowmap, mpad);
}

// Round 15
// 1812.502 us; speedup vs baseline: 1.1799x; 1.1799x over previous
//
#include <hip/hip_runtime.h>
#include <hip/hip_bf16.h>
#include <cstddef>

#define NB 32      // batch
#define NP 196     // pixels
#define NE 2048    // encoder dim
#define ND 512     // decoder/att/emb dim
#define NV 32000   // vocab
#define NL 21
#define NT 20      // decode steps

typedef __attribute__((ext_vector_type(8))) short short8;   // 8 bf16 (4 VGPRs)
typedef __attribute__((ext_vector_type(4))) float f32x4;

__device__ __forceinline__ unsigned short f2b(float f) {
    __hip_bfloat16 h = __float2bfloat16(f);      // RNE
    return *reinterpret_cast<unsigned short*>(&h);
}
__device__ __forceinline__ float b2f_lo(unsigned int u) {
    union { unsigned int i; float f; } v; v.i = u << 16; return v.f;
}
__device__ __forceinline__ float b2f_hi(unsigned int u) {
    union { unsigned int i; float f; } v; v.i = u & 0xffff0000u; return v.f;
}

// ---------------- setup ----------------

__global__ void k_sort(const int* __restrict__ lens, int* __restrict__ sind, int* __restrict__ dlens,
                       int* __restrict__ rowmap, int* __restrict__ mpad, unsigned* __restrict__ cnt)
{
    int i = threadIdx.x;
    if (i < NB) {
        int li = lens[i];
        int r = 0;
        for (int j = 0; j < NB; ++j) {
            int lj = lens[j];
            if (lj > li || (lj == li && j < i)) ++r;
        }
        sind[r] = i;
        dlens[r] = li - 1;
    }
    __syncthreads();
    if (i == 0) {
        int c = 0;
        for (int t = 0; t < NT; ++t)
            for (int b = 0; b < NB; ++b)
                if (t < dlens[b]) rowmap[c++] = t * NB + b;
        int pad = (c + 63) & ~63;
        for (int r = c; r < pad; ++r) rowmap[r] = -1;
        mpad[0] = pad;
        cnt[0] = 0u;
    }
}

__global__ __launch_bounds__(256) void k_mean(const float* __restrict__ enc, const int* __restrict__ sind,
                                              float* __restrict__ mean_enc)
{
    int b = blockIdx.y;
    int k = blockIdx.x * 256 + threadIdx.x;
    const float* e = enc + (size_t)sind[b] * NP * NE + k;
    float s0 = 0.f, s1 = 0.f, s2 = 0.f, s3 = 0.f;
    for (int p = 0; p < NP; p += 4) {
        s0 += e[(size_t)(p + 0) * NE];
        s1 += e[(size_t)(p + 1) * NE];
        s2 += e[(size_t)(p + 2) * NE];
        s3 += e[(size_t)(p + 3) * NE];
    }
    mean_enc[(size_t)b * NE + k] = (s0 + s1 + s2 + s3) * (1.0f / NP);
}

__global__ __launch_bounds__(256) void k_zero(const int* __restrict__ dlens, float* __restrict__ out)
{
    int b = blockIdx.x / NT, t = blockIdx.x % NT;
    if (t < dlens[b]) return;
    float4 z = {0.f, 0.f, 0.f, 0.f};
    float4* row = (float4*)(out + ((size_t)b * NT + t) * NV);
    for (int i = threadIdx.x; i < NV / 4; i += 256) row[i] = z;
}

// ---------------- h0/c0 skinny GEMM, split-K=8 (grid 16 x 8) -> partials in spart ----------------
__global__ __launch_bounds__(256) void gemm_skinny_split(
    const float* __restrict__ A0, const float* __restrict__ W0a, const float* __restrict__ W0b,
    float* __restrict__ spart)
{
    __shared__ float As[32][32];
    __shared__ float Ws[64][33];
    int n0 = blockIdx.x * 64;
    int ks = blockIdx.y;
    int tid = threadIdx.x;
    int lb = tid / 8, lkq = tid % 8;
    int b4 = (tid / 32) * 4, nl = (tid % 32) * 2;
    float acc[4][2] = {};
    for (int kt = ks * 256; kt < ks * 256 + 256; kt += 32) {
        float4 a4 = *reinterpret_cast<const float4*>(A0 + (size_t)lb * NE + kt + lkq * 4);
        As[lkq * 4 + 0][lb] = a4.x; As[lkq * 4 + 1][lb] = a4.y;
        As[lkq * 4 + 2][lb] = a4.z; As[lkq * 4 + 3][lb] = a4.w;
        #pragma unroll
        for (int r = 0; r < 2; ++r) {
            int s = tid + r * 256;
            int n_l = s / 8, kq = s % 8;
            int ng = n0 + n_l;
            const float* wrow = (ng < 512) ? (W0a + (size_t)ng * NE)
                                           : (W0b + (size_t)(ng - 512) * NE);
            float4 w4 = *reinterpret_cast<const float4*>(wrow + kt + kq * 4);
            Ws[n_l][kq * 4 + 0] = w4.x; Ws[n_l][kq * 4 + 1] = w4.y;
            Ws[n_l][kq * 4 + 2] = w4.z; Ws[n_l][kq * 4 + 3] = w4.w;
        }
        __syncthreads();
        #pragma unroll
        for (int k = 0; k < 32; ++k) {
            float4 av = *reinterpret_cast<const float4*>(&As[k][b4]);
            float w0 = Ws[nl][k], w1 = Ws[nl + 1][k];
            acc[0][0] += av.x * w0; acc[0][1] += av.x * w1;
            acc[1][0] += av.y * w0; acc[1][1] += av.y * w1;
            acc[2][0] += av.z * w0; acc[2][1] += av.z * w1;
            acc[3][0] += av.w * w0; acc[3][1] += av.w * w1;
        }
        __syncthreads();
    }
    float* Cp = spart + (size_t)ks * NB * 1024;
    #pragma unroll
    for (int j = 0; j < 2; ++j)
        #pragma unroll
        for (int i = 0; i < 4; ++i)
            Cp[(size_t)(b4 + i) * 1024 + n0 + nl + j] = acc[i][j];
}

// combine partials + bias -> hc; seed xh h-part (grid NB)
__global__ __launch_bounds__(256) void k_hc0(
    const float* __restrict__ spart, const float* __restrict__ ba, const float* __restrict__ bb,
    float* __restrict__ hc, float* __restrict__ xh)
{
    int b = blockIdx.x;
    for (int ng = threadIdx.x; ng < 1024; ng += 256) {
        float s = (ng < 512) ? ba[ng] : bb[ng - 512];
        #pragma unroll
        for (int ks = 0; ks < 8; ++ks)
            s += spart[(size_t)ks * NB * 1024 + (size_t)b * 1024 + ng];
        hc[(size_t)b * 1024 + ng] = s;
        if (ng < 512) xh[(size_t)b * 3072 + 2560 + ng] = s;
    }
}

// ---------------- att1 GEMM (bf16 MFMA), XCD-swizzled ----------------
__global__ __launch_bounds__(256) void gemm_att1_mfma(
    const float* __restrict__ enc, const float* __restrict__ W_ea,
    const float* __restrict__ bias, unsigned short* __restrict__ att1B,
    const int* __restrict__ sind)
{
    int fid = blockIdx.x;
    int c = fid & 7, x = (fid >> 3) & 7, pg = fid >> 6;
    int p = pg * 8 + c;
    if (p >= 98) return;
    int bm0 = p * 64, bn0 = x * 64;
    __shared__ unsigned short As[64][40];
    __shared__ unsigned short Bs[64][40];
    int tid = threadIdx.x;
    int w = tid >> 6, lane = tid & 63;
    int srow = tid >> 2, schunk = (tid & 3) * 8;
    int mg = bm0 + srow;
    int bidx = mg / NP, pp = mg - bidx * NP;
    const float* arow = enc + ((size_t)sind[bidx] * NP + pp) * NE + schunk;
    const float* brow = W_ea + (size_t)(bn0 + srow) * NE + schunk;
    int frow = lane & 15, fk = (lane >> 4) * 8;
    f32x4 acc[4] = {};
    for (int kt = 0; kt < NE; kt += 32) {
        float4 a0 = *reinterpret_cast<const float4*>(arow + kt);
        float4 a1 = *reinterpret_cast<const float4*>(arow + kt + 4);
        float4 b0 = *reinterpret_cast<const float4*>(brow + kt);
        float4 b1 = *reinterpret_cast<const float4*>(brow + kt + 4);
        uint4 av, bv;
        av.x = f2b(a0.x) | ((unsigned)f2b(a0.y) << 16);
        av.y = f2b(a0.z) | ((unsigned)f2b(a0.w) << 16);
        av.z = f2b(a1.x) | ((unsigned)f2b(a1.y) << 16);
        av.w = f2b(a1.z) | ((unsigned)f2b(a1.w) << 16);
        bv.x = f2b(b0.x) | ((unsigned)f2b(b0.y) << 16);
        bv.y = f2b(b0.z) | ((unsigned)f2b(b0.w) << 16);
        bv.z = f2b(b1.x) | ((unsigned)f2b(b1.y) << 16);
        bv.w = f2b(b1.z) | ((unsigned)f2b(b1.w) << 16);
        *reinterpret_cast<uint4*>(&As[srow][schunk]) = av;
        *reinterpret_cast<uint4*>(&Bs[srow][schunk]) = bv;
        __syncthreads();
        short8 af = *reinterpret_cast<const short8*>(&As[w * 16 + frow][fk]);
        #pragma unroll
        for (int n = 0; n < 4; ++n) {
            short8 bf = *reinterpret_cast<const short8*>(&Bs[n * 16 + frow][fk]);
            acc[n] = __builtin_amdgcn_mfma_f32_16x16x32_bf16(af, bf, acc[n], 0, 0, 0);
        }
        __syncthreads();
    }
    int crow = bm0 + w * 16 + (lane >> 4) * 4;
    int ccol0 = lane & 15;
    #pragma unroll
    for (int n = 0; n < 4; ++n) {
        int col = bn0 + n * 16 + ccol0;
        float bb2 = bias[col];
        #pragma unroll
        for (int i = 0; i < 4; ++i)
            att1B[(size_t)(crow + i) * ND + col] = f2b(acc[n][i] + bb2);
    }
}

// ---------------- preds GEMM (bf16 MFMA), XCD-swizzled ----------------
__global__ __launch_bounds__(256) void gemm_preds_mfma(
    const unsigned short* __restrict__ hseqB, const float* __restrict__ W_fc,
    const float* __restrict__ bias, float* __restrict__ out,
    const int* __restrict__ rowmap, const int* __restrict__ mpad)
{
    int fid = blockIdx.x;
    int c = fid & 7;
    int rem = fid >> 3;
    int m = rem % 10, g = rem / 10;
    int n = g * 8 + c;
    if (n >= 250) return;
    int bm0 = m * 64;
    if (bm0 >= mpad[0]) return;
    int bn0 = n * 128;
    __shared__ unsigned short As[64][40];
    __shared__ unsigned short Bs[128][40];
    int tid = threadIdx.x;
    int w = tid >> 6, lane = tid & 63;
    int srow = tid >> 2, schunk = (tid & 3) * 8;
    int rid = rowmap[bm0 + srow];
    const unsigned short* aptr = hseqB + (size_t)(rid < 0 ? 0 : rid) * ND + schunk;
    const float* bptr0 = W_fc + (size_t)(bn0 + srow) * ND + schunk;
    const float* bptr1 = W_fc + (size_t)(bn0 + 64 + srow) * ND + schunk;
    int frow = lane & 15, fk = (lane >> 4) * 8;
    f32x4 acc[8] = {};
    for (int kt = 0; kt < ND; kt += 32) {
        uint4 av = *reinterpret_cast<const uint4*>(aptr + kt);
        float4 c0 = *reinterpret_cast<const float4*>(bptr0 + kt);
        float4 c1 = *reinterpret_cast<const float4*>(bptr0 + kt + 4);
        float4 d0 = *reinterpret_cast<const float4*>(bptr1 + kt);
        float4 d1 = *reinterpret_cast<const float4*>(bptr1 + kt + 4);
        uint4 bv0, bv1;
        bv0.x = f2b(c0.x) | ((unsigned)f2b(c0.y) << 16);
        bv0.y = f2b(c0.z) | ((unsigned)f2b(c0.w) << 16);
        bv0.z = f2b(c1.x) | ((unsigned)f2b(c1.y) << 16);
        bv0.w = f2b(c1.z) | ((unsigned)f2b(c1.w) << 16);
        bv1.x = f2b(d0.x) | ((unsigned)f2b(d0.y) << 16);
        bv1.y = f2b(d0.z) | ((unsigned)f2b(d0.w) << 16);
        bv1.z = f2b(d1.x) | ((unsigned)f2b(d1.y) << 16);
        bv1.w = f2b(d1.z) | ((unsigned)f2b(d1.w) << 16);
        *reinterpret_cast<uint4*>(&As[srow][schunk]) = av;
        *reinterpret_cast<uint4*>(&Bs[srow][schunk]) = bv0;
        *reinterpret_cast<uint4*>(&Bs[64 + srow][schunk]) = bv1;
        __syncthreads();
        short8 af = *reinterpret_cast<const short8*>(&As[w * 16 + frow][fk]);
        #pragma unroll
        for (int nn = 0; nn < 8; ++nn) {
            short8 bf = *reinterpret_cast<const short8*>(&Bs[nn * 16 + frow][fk]);
            acc[nn] = __builtin_amdgcn_mfma_f32_16x16x32_bf16(af, bf, acc[nn], 0, 0, 0);
        }
        __syncthreads();
    }
    int rl0 = w * 16 + (lane >> 4) * 4;
    int ccol0 = lane & 15;
    #pragma unroll
    for (int i = 0; i < 4; ++i) {
        int rm = rowmap[bm0 + rl0 + i];
        if (rm < 0) continue;
        int t = rm / NB, b = rm % NB;
        float* orow = out + ((size_t)b * NT + t) * NV;
        #pragma unroll
        for (int nn = 0; nn < 8; ++nn) {
            int col = bn0 + nn * 16 + ccol0;
            orow[col] = acc[nn][i] + bias[col];
        }
    }
}

// ---------------- k_attg: attg[32][2560] = h @ [W_da;W_fb]^T + [b_da;b_fb] (40 blocks) ----------------
__global__ __launch_bounds__(256) void k_attg(
    const float* __restrict__ hc, const float* __restrict__ W_da, const float* __restrict__ W_fb,
    const float* __restrict__ b_da, const float* __restrict__ b_fb, float* __restrict__ attg)
{
    __shared__ float As[32][32];
    __shared__ float Ws[64][33];
    int n0 = blockIdx.x * 64;
    int tid = threadIdx.x;
    int lb = tid / 8, lkq = tid % 8;
    int b4 = (tid / 32) * 4, nl = (tid % 32) * 2;
    float acc[4][2] = {};
    for (int kt = 0; kt < 512; kt += 32) {
        float4 a4 = *reinterpret_cast<const float4*>(hc + (size_t)lb * 1024 + kt + lkq * 4);
        As[lkq * 4 + 0][lb] = a4.x; As[lkq * 4 + 1][lb] = a4.y;
        As[lkq * 4 + 2][lb] = a4.z; As[lkq * 4 + 3][lb] = a4.w;
        #pragma unroll
        for (int r = 0; r < 2; ++r) {
            int s = tid + r * 256;
            int n_l = s / 8, kq = s % 8;
            int ng = n0 + n_l;
            const float* wrow = (ng < 512) ? (W_da + (size_t)ng * 512)
                                           : (W_fb + (size_t)(ng - 512) * 512);
            float4 w4 = *reinterpret_cast<const float4*>(wrow + kt + kq * 4);
            Ws[n_l][kq * 4 + 0] = w4.x; Ws[n_l][kq * 4 + 1] = w4.y;
            Ws[n_l][kq * 4 + 2] = w4.z; Ws[n_l][kq * 4 + 3] = w4.w;
        }
        __syncthreads();
        #pragma unroll
        for (int k = 0; k < 32; ++k) {
            float4 av = *reinterpret_cast<const float4*>(&As[k][b4]);
            float w0 = Ws[nl][k], w1 = Ws[nl + 1][k];
            acc[0][0] += av.x * w0; acc[0][1] += av.x * w1;
            acc[1][0] += av.y * w0; acc[1][1] += av.y * w1;
            acc[2][0] += av.z * w0; acc[2][1] += av.z * w1;
            acc[3][0] += av.w * w0; acc[3][1] += av.w * w1;
        }
        __syncthreads();
    }
    #pragma unroll
    for (int j = 0; j < 2; ++j) {
        int ng = n0 + nl + j;
        float bias = (ng < 512) ? b_da[ng] : b_fb[ng - 512];
        #pragma unroll
        for (int i = 0; i < 4; ++i)
            attg[(size_t)(b4 + i) * 2560 + ng] = acc[i][j] + bias;
    }
}

// ---------------- k_e: e scores from bf16 att1 (grid 7 x 32) ----------------
__global__ __launch_bounds__(256) void k_e(
    const unsigned short* __restrict__ att1B, const float* __restrict__ attg,
    const float* __restrict__ w_fa, const float* __restrict__ b_fa,
    float* __restrict__ e)
{
    __shared__ float att2s[ND];
    __shared__ float wfas[ND];
    int b = blockIdx.y, tid = threadIdx.x;
    const float* ag = attg + (size_t)b * 2560;
    for (int d = tid; d < ND; d += 256) { att2s[d] = ag[d]; wfas[d] = w_fa[d]; }
    __syncthreads();
    int w = tid >> 6, lane = tid & 63;
    int p0 = blockIdx.x * 28;
    const unsigned short* a1 = att1B + ((size_t)b * NP + p0) * ND;
    #pragma unroll
    for (int i = 0; i < 7; ++i) {
        int p = w + 4 * i;
        const unsigned short* row = a1 + (size_t)p * ND;
        float s = 0.f;
        #pragma unroll
        for (int j = 0; j < 2; ++j) {
            int d = j * 256 + lane * 4;
            uint2 u = *reinterpret_cast<const uint2*>(row + d);   // 4 bf16
            float v0 = b2f_lo(u.x), v1 = b2f_hi(u.x);
            float v2 = b2f_lo(u.y), v3 = b2f_hi(u.y);
            float4 a2 = *reinterpret_cast<const float4*>(&att2s[d]);
            float4 wf = *reinterpret_cast<const float4*>(&wfas[d]);
            s += fmaxf(v0 + a2.x, 0.f) * wf.x + fmaxf(v1 + a2.y, 0.f) * wf.y
               + fmaxf(v2 + a2.z, 0.f) * wf.z + fmaxf(v3 + a2.w, 0.f) * wf.w;
        }
        for (int off = 32; off > 0; off >>= 1) s += __shfl_down(s, off);
        if (lane == 0) e[(size_t)b * NP + p0 + p] = s + b_fa[0];
    }
}

// ---------------- k_awe: softmax + awe + gate + xh + gates bias-init (grid 8 x 32) ----------------
__global__ __launch_bounds__(256) void k_awe(
    const float* __restrict__ enc, const int* __restrict__ sind, const int* __restrict__ dlens,
    const int* __restrict__ caps, const float* __restrict__ emb_W,
    const float* __restrict__ e, const float* __restrict__ attg,
    const float* __restrict__ b_ih, const float* __restrict__ b_hh,
    float* __restrict__ xh, float* __restrict__ gates,
    float* __restrict__ out_alpha, int t)
{
    __shared__ float es[256];
    __shared__ float red[256];
    int kc = blockIdx.x, b = blockIdx.y, tid = threadIdx.x;
    float ev = -1e30f;
    if (tid < NP) { float v = e[(size_t)b * NP + tid]; es[tid] = v; ev = v; }
    red[tid] = ev; __syncthreads();
    for (int s2 = 128; s2 > 0; s2 >>= 1) { if (tid < s2) red[tid] = fmaxf(red[tid], red[tid + s2]); __syncthreads(); }
    float m = red[0]; __syncthreads();
    float xe = (tid < NP) ? expf(es[tid] - m) : 0.f;
    red[tid] = xe; __syncthreads();
    for (int s2 = 128; s2 > 0; s2 >>= 1) { if (tid < s2) red[tid] += red[tid + s2]; __syncthreads(); }
    float inv = 1.0f / red[0];
    __syncthreads();
    es[tid] = xe * inv;
    __syncthreads();

    // gates bias-init for this (b, kc) slice (k_gates atomicAdds partials on top)
    int n = kc * 256 + tid;
    gates[(size_t)b * 2048 + n] = b_ih[n] + b_hh[n];

    int k = kc * 256 + tid;
    const float* ec = enc + (size_t)sind[b] * NP * NE + k;
    float s0 = 0.f, s1 = 0.f, s2v = 0.f, s3 = 0.f;
    #pragma unroll 4
    for (int p = 0; p < NP; p += 4) {
        s0 += es[p + 0] * ec[(size_t)(p + 0) * NE];
        s1 += es[p + 1] * ec[(size_t)(p + 1) * NE];
        s2v += es[p + 2] * ec[(size_t)(p + 2) * NE];
        s3 += es[p + 3] * ec[(size_t)(p + 3) * NE];
    }
    float awe = (s0 + s1) + (s2v + s3);
    float gp = attg[(size_t)b * 2560 + 512 + k];      // includes b_fb
    float gate = 1.f / (1.f + expf(-gp));
    xh[(size_t)b * 3072 + 512 + k] = gate * awe;
    if (kc == 0) {
        bool live = (t < dlens[b]);
        if (tid < NP) out_alpha[((size_t)b * NT + t) * NP + tid] = live ? es[tid] : 0.f;
        const float* er = emb_W + (size_t)caps[sind[b] * NL + t] * ND;
        xh[(size_t)b * 3072 + tid] = er[tid];
        xh[(size_t)b * 3072 + 256 + tid] = er[256 + tid];
    }
}

// ---------------- k_gates: gates GEMM (atomicAdd into bias-initialized gates)
//                  + fused LSTM cell via arrival-counter finisher (blocks 0..31) ----------------
__global__ __launch_bounds__(256) void k_gates(
    const float* __restrict__ xh, const float* __restrict__ W_ih, const float* __restrict__ W_hh,
    float* __restrict__ gates, unsigned* __restrict__ cnt, const int* __restrict__ dlens,
    float* __restrict__ hc, unsigned short* __restrict__ hseqB, float* __restrict__ xhw, int t)
{
    __shared__ float smem[3200];
    int blk = blockIdx.x, tid = threadIdx.x;
    int nt = blk & 31, ks = blk >> 5;
    float* As = smem;
    float (*Ws)[33] = (float(*)[33])(smem + 1024);
    int n0 = nt * 64;
    int lb = tid / 8, lkq = tid % 8;
    int b4 = (tid / 32) * 4, nl = (tid % 32) * 2;
    float acc[4][2] = {};
    for (int kt = ks * 768; kt < ks * 768 + 768; kt += 32) {
        float4 a4 = *reinterpret_cast<const float4*>(xh + (size_t)lb * 3072 + kt + lkq * 4);
        As[(lkq * 4 + 0) * 32 + lb] = a4.x; As[(lkq * 4 + 1) * 32 + lb] = a4.y;
        As[(lkq * 4 + 2) * 32 + lb] = a4.z; As[(lkq * 4 + 3) * 32 + lb] = a4.w;
        #pragma unroll
        for (int r = 0; r < 2; ++r) {
            int s = tid + r * 256;
            int n_l = s / 8, kq = s % 8;
            int ng = n0 + n_l;
            int kk = kt + kq * 4;
            const float* wrow = (kk < 2560) ? (W_ih + (size_t)ng * 2560 + kk)
                                            : (W_hh + (size_t)ng * 512 + (kk - 2560));
            float4 w4 = *reinterpret_cast<const float4*>(wrow);
            Ws[n_l][kq * 4 + 0] = w4.x; Ws[n_l][kq * 4 + 1] = w4.y;
            Ws[n_l][kq * 4 + 2] = w4.z; Ws[n_l][kq * 4 + 3] = w4.w;
        }
        __syncthreads();
        #pragma unroll
        for (int k = 0; k < 32; ++k) {
            float4 av = *reinterpret_cast<const float4*>(&As[k * 32 + b4]);
            float w0 = Ws[nl][k], w1 = Ws[nl + 1][k];
            acc[0][0] += av.x * w0; acc[0][1] += av.x * w1;
            acc[1][0] += av.y * w0; acc[1][1] += av.y * w1;
            acc[2][0] += av.z * w0; acc[2][1] += av.z * w1;
            acc[3][0] += av.w * w0; acc[3][1] += av.w * w1;
        }
        __syncthreads();
    }
    #pragma unroll
    for (int j = 0; j < 2; ++j)
        #pragma unroll
        for (int i = 0; i < 4; ++i)
            atomicAdd(&gates[(size_t)(b4 + i) * 2048 + n0 + nl + j], acc[i][j]);

    // arrival counter (device scope); blocks 0..31 become the cell finishers
    __syncthreads();
    if (tid == 0)
        __hip_atomic_fetch_add(cnt, 1u, __ATOMIC_ACQ_REL, __HIP_MEMORY_SCOPE_AGENT);
    if (blk >= 32) return;
    if (tid == 0) {
        unsigned target = 128u * (unsigned)(t + 1);
        unsigned iters = 0;
        while (__hip_atomic_load(cnt, __ATOMIC_ACQUIRE, __HIP_MEMORY_SCOPE_AGENT) < target) {
            __builtin_amdgcn_s_sleep(1);
            if (++iters > 200000000u) break;   // failsafe; blocks are always co-resident
        }
    }
    __syncthreads();
    int b = blk;
    bool live = (t < dlens[b]);
    for (int d = tid; d < ND; d += 256) {
        float g0 = __hip_atomic_load(&gates[(size_t)b * 2048 + d],        __ATOMIC_RELAXED, __HIP_MEMORY_SCOPE_AGENT);
        float g1 = __hip_atomic_load(&gates[(size_t)b * 2048 + 512 + d],  __ATOMIC_RELAXED, __HIP_MEMORY_SCOPE_AGENT);
        float g2 = __hip_atomic_load(&gates[(size_t)b * 2048 + 1024 + d], __ATOMIC_RELAXED, __HIP_MEMORY_SCOPE_AGENT);
        float g3 = __hip_atomic_load(&gates[(size_t)b * 2048 + 1536 + d], __ATOMIC_RELAXED, __HIP_MEMORY_SCOPE_AGENT);
        float ig = 1.f / (1.f + expf(-g0));
        float fg = 1.f / (1.f + expf(-g1));
        float gt = tanhf(g2);
        float og = 1.f / (1.f + expf(-g3));
        float c_old = hc[(size_t)b * 1024 + 512 + d];
        float c_new = fg * c_old + ig * gt;
        float h_new = og * tanhf(c_new);
        hseqB[((size_t)t * NB + b) * ND + d] = f2b(h_new);
        if (live) {
            hc[(size_t)b * 1024 + d] = h_new;
            hc[(size_t)b * 1024 + 512 + d] = c_new;
            xhw[(size_t)b * 3072 + 2560 + d] = h_new;
        }
    }
}

// ---------------- launcher ----------------
extern "C" void kernel_launch(void* const* d_in, const int* in_sizes, int n_in,
                              void* d_out, int out_size, void* d_ws, size_t ws_size,
                              hipStream_t stream)
{
    const float* enc   = (const float*)d_in[0];
    const int*   caps  = (const int*)d_in[1];
    const int*   clens = (const int*)d_in[2];
    const float* emb_W = (const float*)d_in[3];
    const float* W_ea  = (const float*)d_in[4];
    const float* b_ea  = (const float*)d_in[5];
    const float* W_da  = (const float*)d_in[6];
    const float* b_da  = (const float*)d_in[7];
    const float* w_fa  = (const float*)d_in[8];
    const float* b_fa  = (const float*)d_in[9];
    const float* W_ih  = (const float*)d_in[10];
    const float* b_ih  = (const float*)d_in[11];
    const float* W_hh  = (const float*)d_in[12];
    const float* b_hh  = (const float*)d_in[13];
    const float* W_h0  = (const float*)d_in[14];
    const float* b_h0  = (const float*)d_in[15];
    const float* W_c0  = (const float*)d_in[16];
    const float* b_c0  = (const float*)d_in[17];
    const float* W_fb  = (const float*)d_in[18];
    const float* b_fb  = (const float*)d_in[19];
    const float* W_fc  = (const float*)d_in[20];
    const float* b_fc  = (const float*)d_in[21];

    float* out = (float*)d_out;
    float* out_alpha = out + (size_t)NB * NT * NV;

    int* iws    = (int*)d_ws;
    int* sind   = iws;
    int* dlens  = iws + 32;
    int* rowmap = iws + 64;
    int* mpad   = iws + 704;
    unsigned* cnt = (unsigned*)(iws + 706);
    float* base = (float*)d_ws + 1024;
    float* mean_enc = base;                         // 65536
    float* hc    = mean_enc + NB * NE;              // 32768
    float* attg  = hc + NB * 1024;                  // 81920
    float* xh    = attg + NB * 2560;                // 98304
    float* e     = xh + NB * 3072;                  // 6272
    float* gates = e + NB * NP + 128;               // 65536 used; 262144 reserved (spart at setup)
    unsigned short* att1B = (unsigned short*)(gates + 262144);          // 6272*512 bf16
    unsigned short* hseqB = att1B + (size_t)NB * NP * ND;               // 640*512 bf16

    k_sort<<<1, 64, 0, stream>>>(clens, sind, dlens, rowmap, mpad, cnt);
    k_zero<<<NB * NT, 256, 0, stream>>>(dlens, out);
    k_mean<<<dim3(NE / 256, NB), 256, 0, stream>>>(enc, sind, mean_enc);
    gemm_skinny_split<<<dim3(16, 8), 256, 0, stream>>>(mean_enc, W_h0, W_c0, gates);
    k_hc0<<<dim3(NB), 256, 0, stream>>>(gates, b_h0, b_c0, hc, xh);
    gemm_att1_mfma<<<dim3(832), 256, 0, stream>>>(enc, W_ea, b_ea, att1B, sind);

    for (int t = 0; t < NT; ++t) {
        k_attg<<<dim3(40), 256, 0, stream>>>(hc, W_da, W_fb, b_da, b_fb, attg);
        k_e<<<dim3(7, NB), 256, 0, stream>>>(att1B, attg, w_fa, b_fa, e);
        k_awe<<<dim3(8, NB), 256, 0, stream>>>(enc, sind, dlens, caps, emb_W,
                                               e, attg, b_ih, b_hh,
                                               xh, gates, out_alpha, t);
        k_gates<<<dim3(128), 256, 0, stream>>>(xh, W_ih, W_hh, gates, cnt, dlens,
                                               hc, hseqB, xh, t);
    }

    gemm_preds_mfma<<<dim3(2560), 256, 0, stream>>>(hseqB, W_fc, b_fc, out, rowmap, mpad);
}

// Round 16
// 1804.968 us; speedup vs baseline: 1.1848x; 1.0042x over previous
//
#include <hip/hip_runtime.h>
#include <hip/hip_bf16.h>
#include <cstddef>

#define NB 32      // batch
#define NP 196     // pixels
#define NE 2048    // encoder dim
#define ND 512     // decoder/att/emb dim
#define NV 32000   // vocab
#define NL 21
#define NT 20      // decode steps

typedef __attribute__((ext_vector_type(8))) short short8;   // 8 bf16 (4 VGPRs)
typedef __attribute__((ext_vector_type(4))) float f32x4;

__device__ __forceinline__ unsigned short f2b(float f) {
    __hip_bfloat16 h = __float2bfloat16(f);      // RNE
    return *reinterpret_cast<unsigned short*>(&h);
}
__device__ __forceinline__ float b2f(unsigned short u) {
    union { unsigned int i; float f; } v; v.i = (unsigned)u << 16; return v.f;
}
__device__ __forceinline__ float b2f_lo(unsigned int u) {
    union { unsigned int i; float f; } v; v.i = u << 16; return v.f;
}
__device__ __forceinline__ float b2f_hi(unsigned int u) {
    union { unsigned int i; float f; } v; v.i = u & 0xffff0000u; return v.f;
}

// ---------------- setup ----------------

__global__ void k_sort(const int* __restrict__ lens, int* __restrict__ sind, int* __restrict__ dlens,
                       int* __restrict__ rowmap, int* __restrict__ mpad)
{
    int i = threadIdx.x;
    if (i < NB) {
        int li = lens[i];
        int r = 0;
        for (int j = 0; j < NB; ++j) {
            int lj = lens[j];
            if (lj > li || (lj == li && j < i)) ++r;
        }
        sind[r] = i;
        dlens[r] = li - 1;
    }
    __syncthreads();
    if (i == 0) {
        int c = 0;
        for (int t = 0; t < NT; ++t)
            for (int b = 0; b < NB; ++b)
                if (t < dlens[b]) rowmap[c++] = t * NB + b;
        int pad = (c + 63) & ~63;
        for (int r = c; r < pad; ++r) rowmap[r] = -1;
        mpad[0] = pad;
    }
}

// enc (sorted) -> bf16 copy: encB[b] = bf16(enc[sind[b]])   (grid 6272)
__global__ __launch_bounds__(256) void k_conv_enc(
    const float* __restrict__ enc, const int* __restrict__ sind,
    unsigned short* __restrict__ encB)
{
    int idx = (blockIdx.x * 256 + threadIdx.x) * 8;
    int b = idx / (NP * NE), rem = idx - b * (NP * NE);
    const float* src = enc + (size_t)sind[b] * NP * NE + rem;
    float4 a = *reinterpret_cast<const float4*>(src);
    float4 c = *reinterpret_cast<const float4*>(src + 4);
    uint4 o;
    o.x = f2b(a.x) | ((unsigned)f2b(a.y) << 16);
    o.y = f2b(a.z) | ((unsigned)f2b(a.w) << 16);
    o.z = f2b(c.x) | ((unsigned)f2b(c.y) << 16);
    o.w = f2b(c.z) | ((unsigned)f2b(c.w) << 16);
    *reinterpret_cast<uint4*>(encB + idx) = o;
}

__global__ __launch_bounds__(256) void k_mean(const float* __restrict__ enc, const int* __restrict__ sind,
                                              float* __restrict__ mean_enc)
{
    int b = blockIdx.y;
    int k = blockIdx.x * 256 + threadIdx.x;
    const float* e = enc + (size_t)sind[b] * NP * NE + k;
    float s0 = 0.f, s1 = 0.f, s2 = 0.f, s3 = 0.f;
    for (int p = 0; p < NP; p += 4) {
        s0 += e[(size_t)(p + 0) * NE];
        s1 += e[(size_t)(p + 1) * NE];
        s2 += e[(size_t)(p + 2) * NE];
        s3 += e[(size_t)(p + 3) * NE];
    }
    mean_enc[(size_t)b * NE + k] = (s0 + s1 + s2 + s3) * (1.0f / NP);
}

__global__ __launch_bounds__(256) void k_zero(const int* __restrict__ dlens, float* __restrict__ out)
{
    int b = blockIdx.x / NT, t = blockIdx.x % NT;
    if (t < dlens[b]) return;
    float4 z = {0.f, 0.f, 0.f, 0.f};
    float4* row = (float4*)(out + ((size_t)b * NT + t) * NV);
    for (int i = threadIdx.x; i < NV / 4; i += 256) row[i] = z;
}

// ---------------- h0/c0 skinny GEMM, split-K=8 (grid 16 x 8) -> partials in spart ----------------
__global__ __launch_bounds__(256) void gemm_skinny_split(
    const float* __restrict__ A0, const float* __restrict__ W0a, const float* __restrict__ W0b,
    float* __restrict__ spart)
{
    __shared__ float As[32][32];
    __shared__ float Ws[64][33];
    int n0 = blockIdx.x * 64;
    int ks = blockIdx.y;
    int tid = threadIdx.x;
    int lb = tid / 8, lkq = tid % 8;
    int b4 = (tid / 32) * 4, nl = (tid % 32) * 2;
    float acc[4][2] = {};
    for (int kt = ks * 256; kt < ks * 256 + 256; kt += 32) {
        float4 a4 = *reinterpret_cast<const float4*>(A0 + (size_t)lb * NE + kt + lkq * 4);
        As[lkq * 4 + 0][lb] = a4.x; As[lkq * 4 + 1][lb] = a4.y;
        As[lkq * 4 + 2][lb] = a4.z; As[lkq * 4 + 3][lb] = a4.w;
        #pragma unroll
        for (int r = 0; r < 2; ++r) {
            int s = tid + r * 256;
            int n_l = s / 8, kq = s % 8;
            int ng = n0 + n_l;
            const float* wrow = (ng < 512) ? (W0a + (size_t)ng * NE)
                                           : (W0b + (size_t)(ng - 512) * NE);
            float4 w4 = *reinterpret_cast<const float4*>(wrow + kt + kq * 4);
            Ws[n_l][kq * 4 + 0] = w4.x; Ws[n_l][kq * 4 + 1] = w4.y;
            Ws[n_l][kq * 4 + 2] = w4.z; Ws[n_l][kq * 4 + 3] = w4.w;
        }
        __syncthreads();
        #pragma unroll
        for (int k = 0; k < 32; ++k) {
            float4 av = *reinterpret_cast<const float4*>(&As[k][b4]);
            float w0 = Ws[nl][k], w1 = Ws[nl + 1][k];
            acc[0][0] += av.x * w0; acc[0][1] += av.x * w1;
            acc[1][0] += av.y * w0; acc[1][1] += av.y * w1;
            acc[2][0] += av.z * w0; acc[2][1] += av.z * w1;
            acc[3][0] += av.w * w0; acc[3][1] += av.w * w1;
        }
        __syncthreads();
    }
    float* Cp = spart + (size_t)ks * NB * 1024;
    #pragma unroll
    for (int j = 0; j < 2; ++j)
        #pragma unroll
        for (int i = 0; i < 4; ++i)
            Cp[(size_t)(b4 + i) * 1024 + n0 + nl + j] = acc[i][j];
}

// combine partials + bias -> hc; seed xh h-part (grid NB)
__global__ __launch_bounds__(256) void k_hc0(
    const float* __restrict__ spart, const float* __restrict__ ba, const float* __restrict__ bb,
    float* __restrict__ hc, float* __restrict__ xh)
{
    int b = blockIdx.x;
    for (int ng = threadIdx.x; ng < 1024; ng += 256) {
        float s = (ng < 512) ? ba[ng] : bb[ng - 512];
        #pragma unroll
        for (int ks = 0; ks < 8; ++ks)
            s += spart[(size_t)ks * NB * 1024 + (size_t)b * 1024 + ng];
        hc[(size_t)b * 1024 + ng] = s;
        if (ng < 512) xh[(size_t)b * 3072 + 2560 + ng] = s;
    }
}

// ---------------- att1 GEMM (bf16 MFMA), A from encB (pre-sorted bf16), XCD-swizzled ----------------
__global__ __launch_bounds__(256) void gemm_att1_mfma(
    const unsigned short* __restrict__ encB, const float* __restrict__ W_ea,
    const float* __restrict__ bias, unsigned short* __restrict__ att1B)
{
    int fid = blockIdx.x;
    int c = fid & 7, x = (fid >> 3) & 7, pg = fid >> 6;
    int p = pg * 8 + c;
    if (p >= 98) return;
    int bm0 = p * 64, bn0 = x * 64;
    __shared__ unsigned short As[64][40];
    __shared__ unsigned short Bs[64][40];
    int tid = threadIdx.x;
    int w = tid >> 6, lane = tid & 63;
    int srow = tid >> 2, schunk = (tid & 3) * 8;
    const unsigned short* arow = encB + (size_t)(bm0 + srow) * NE + schunk;
    const float* brow = W_ea + (size_t)(bn0 + srow) * NE + schunk;
    int frow = lane & 15, fk = (lane >> 4) * 8;
    f32x4 acc[4] = {};
    for (int kt = 0; kt < NE; kt += 32) {
        uint4 av = *reinterpret_cast<const uint4*>(arow + kt);
        float4 b0 = *reinterpret_cast<const float4*>(brow + kt);
        float4 b1 = *reinterpret_cast<const float4*>(brow + kt + 4);
        uint4 bv;
        bv.x = f2b(b0.x) | ((unsigned)f2b(b0.y) << 16);
        bv.y = f2b(b0.z) | ((unsigned)f2b(b0.w) << 16);
        bv.z = f2b(b1.x) | ((unsigned)f2b(b1.y) << 16);
        bv.w = f2b(b1.z) | ((unsigned)f2b(b1.w) << 16);
        *reinterpret_cast<uint4*>(&As[srow][schunk]) = av;
        *reinterpret_cast<uint4*>(&Bs[srow][schunk]) = bv;
        __syncthreads();
        short8 af = *reinterpret_cast<const short8*>(&As[w * 16 + frow][fk]);
        #pragma unroll
        for (int n = 0; n < 4; ++n) {
            short8 bf = *reinterpret_cast<const short8*>(&Bs[n * 16 + frow][fk]);
            acc[n] = __builtin_amdgcn_mfma_f32_16x16x32_bf16(af, bf, acc[n], 0, 0, 0);
        }
        __syncthreads();
    }
    int crow = bm0 + w * 16 + (lane >> 4) * 4;
    int ccol0 = lane & 15;
    #pragma unroll
    for (int n = 0; n < 4; ++n) {
        int col = bn0 + n * 16 + ccol0;
        float bb2 = bias[col];
        #pragma unroll
        for (int i = 0; i < 4; ++i)
            att1B[(size_t)(crow + i) * ND + col] = f2b(acc[n][i] + bb2);
    }
}

// ---------------- preds GEMM (bf16 MFMA), XCD-swizzled ----------------
__global__ __launch_bounds__(256) void gemm_preds_mfma(
    const unsigned short* __restrict__ hseqB, const float* __restrict__ W_fc,
    const float* __restrict__ bias, float* __restrict__ out,
    const int* __restrict__ rowmap, const int* __restrict__ mpad)
{
    int fid = blockIdx.x;
    int c = fid & 7;
    int rem = fid >> 3;
    int m = rem % 10, g = rem / 10;
    int n = g * 8 + c;
    if (n >= 250) return;
    int bm0 = m * 64;
    if (bm0 >= mpad[0]) return;
    int bn0 = n * 128;
    __shared__ unsigned short As[64][40];
    __shared__ unsigned short Bs[128][40];
    int tid = threadIdx.x;
    int w = tid >> 6, lane = tid & 63;
    int srow = tid >> 2, schunk = (tid & 3) * 8;
    int rid = rowmap[bm0 + srow];
    const unsigned short* aptr = hseqB + (size_t)(rid < 0 ? 0 : rid) * ND + schunk;
    const float* bptr0 = W_fc + (size_t)(bn0 + srow) * ND + schunk;
    const float* bptr1 = W_fc + (size_t)(bn0 + 64 + srow) * ND + schunk;
    int frow = lane & 15, fk = (lane >> 4) * 8;
    f32x4 acc[8] = {};
    for (int kt = 0; kt < ND; kt += 32) {
        uint4 av = *reinterpret_cast<const uint4*>(aptr + kt);
        float4 c0 = *reinterpret_cast<const float4*>(bptr0 + kt);
        float4 c1 = *reinterpret_cast<const float4*>(bptr0 + kt + 4);
        float4 d0 = *reinterpret_cast<const float4*>(bptr1 + kt);
        float4 d1 = *reinterpret_cast<const float4*>(bptr1 + kt + 4);
        uint4 bv0, bv1;
        bv0.x = f2b(c0.x) | ((unsigned)f2b(c0.y) << 16);
        bv0.y = f2b(c0.z) | ((unsigned)f2b(c0.w) << 16);
        bv0.z = f2b(c1.x) | ((unsigned)f2b(c1.y) << 16);
        bv0.w = f2b(c1.z) | ((unsigned)f2b(c1.w) << 16);
        bv1.x = f2b(d0.x) | ((unsigned)f2b(d0.y) << 16);
        bv1.y = f2b(d0.z) | ((unsigned)f2b(d0.w) << 16);
        bv1.z = f2b(d1.x) | ((unsigned)f2b(d1.y) << 16);
        bv1.w = f2b(d1.z) | ((unsigned)f2b(d1.w) << 16);
        *reinterpret_cast<uint4*>(&As[srow][schunk]) = av;
        *reinterpret_cast<uint4*>(&Bs[srow][schunk]) = bv0;
        *reinterpret_cast<uint4*>(&Bs[64 + srow][schunk]) = bv1;
        __syncthreads();
        short8 af = *reinterpret_cast<const short8*>(&As[w * 16 + frow][fk]);
        #pragma unroll
        for (int nn = 0; nn < 8; ++nn) {
            short8 bf = *reinterpret_cast<const short8*>(&Bs[nn * 16 + frow][fk]);
            acc[nn] = __builtin_amdgcn_mfma_f32_16x16x32_bf16(af, bf, acc[nn], 0, 0, 0);
        }
        __syncthreads();
    }
    int rl0 = w * 16 + (lane >> 4) * 4;
    int ccol0 = lane & 15;
    #pragma unroll
    for (int i = 0; i < 4; ++i) {
        int rm = rowmap[bm0 + rl0 + i];
        if (rm < 0) continue;
        int t = rm / NB, b = rm % NB;
        float* orow = out + ((size_t)b * NT + t) * NV;
        #pragma unroll
        for (int nn = 0; nn < 8; ++nn) {
            int col = bn0 + nn * 16 + ccol0;
            orow[col] = acc[nn][i] + bias[col];
        }
    }
}

// ---------------- k_attg: attg[32][2560] = h @ [W_da;W_fb]^T + [b_da;b_fb] (40 blocks) ----------------
__global__ __launch_bounds__(256) void k_attg(
    const float* __restrict__ hc, const float* __restrict__ W_da, const float* __restrict__ W_fb,
    const float* __restrict__ b_da, const float* __restrict__ b_fb, float* __restrict__ attg)
{
    __shared__ float As[32][32];
    __shared__ float Ws[64][33];
    int n0 = blockIdx.x * 64;
    int tid = threadIdx.x;
    int lb = tid / 8, lkq = tid % 8;
    int b4 = (tid / 32) * 4, nl = (tid % 32) * 2;
    float acc[4][2] = {};
    for (int kt = 0; kt < 512; kt += 32) {
        float4 a4 = *reinterpret_cast<const float4*>(hc + (size_t)lb * 1024 + kt + lkq * 4);
        As[lkq * 4 + 0][lb] = a4.x; As[lkq * 4 + 1][lb] = a4.y;
        As[lkq * 4 + 2][lb] = a4.z; As[lkq * 4 + 3][lb] = a4.w;
        #pragma unroll
        for (int r = 0; r < 2; ++r) {
            int s = tid + r * 256;
            int n_l = s / 8, kq = s % 8;
            int ng = n0 + n_l;
            const float* wrow = (ng < 512) ? (W_da + (size_t)ng * 512)
                                           : (W_fb + (size_t)(ng - 512) * 512);
            float4 w4 = *reinterpret_cast<const float4*>(wrow + kt + kq * 4);
            Ws[n_l][kq * 4 + 0] = w4.x; Ws[n_l][kq * 4 + 1] = w4.y;
            Ws[n_l][kq * 4 + 2] = w4.z; Ws[n_l][kq * 4 + 3] = w4.w;
        }
        __syncthreads();
        #pragma unroll
        for (int k = 0; k < 32; ++k) {
            float4 av = *reinterpret_cast<const float4*>(&As[k][b4]);
            float w0 = Ws[nl][k], w1 = Ws[nl + 1][k];
            acc[0][0] += av.x * w0; acc[0][1] += av.x * w1;
            acc[1][0] += av.y * w0; acc[1][1] += av.y * w1;
            acc[2][0] += av.z * w0; acc[2][1] += av.z * w1;
            acc[3][0] += av.w * w0; acc[3][1] += av.w * w1;
        }
        __syncthreads();
    }
    #pragma unroll
    for (int j = 0; j < 2; ++j) {
        int ng = n0 + nl + j;
        float bias = (ng < 512) ? b_da[ng] : b_fb[ng - 512];
        #pragma unroll
        for (int i = 0; i < 4; ++i)
            attg[(size_t)(b4 + i) * 2560 + ng] = acc[i][j] + bias;
    }
}

// ---------------- k_e: e scores from bf16 att1 (grid 7 x 32) ----------------
__global__ __launch_bounds__(256) void k_e(
    const unsigned short* __restrict__ att1B, const float* __restrict__ attg,
    const float* __restrict__ w_fa, const float* __restrict__ b_fa,
    float* __restrict__ e)
{
    __shared__ float att2s[ND];
    __shared__ float wfas[ND];
    int b = blockIdx.y, tid = threadIdx.x;
    const float* ag = attg + (size_t)b * 2560;
    for (int d = tid; d < ND; d += 256) { att2s[d] = ag[d]; wfas[d] = w_fa[d]; }
    __syncthreads();
    int w = tid >> 6, lane = tid & 63;
    int p0 = blockIdx.x * 28;
    const unsigned short* a1 = att1B + ((size_t)b * NP + p0) * ND;
    #pragma unroll
    for (int i = 0; i < 7; ++i) {
        int p = w + 4 * i;
        const unsigned short* row = a1 + (size_t)p * ND;
        float s = 0.f;
        #pragma unroll
        for (int j = 0; j < 2; ++j) {
            int d = j * 256 + lane * 4;
            uint2 u = *reinterpret_cast<const uint2*>(row + d);   // 4 bf16
            float v0 = b2f_lo(u.x), v1 = b2f_hi(u.x);
            float v2 = b2f_lo(u.y), v3 = b2f_hi(u.y);
            float4 a2 = *reinterpret_cast<const float4*>(&att2s[d]);
            float4 wf = *reinterpret_cast<const float4*>(&wfas[d]);
            s += fmaxf(v0 + a2.x, 0.f) * wf.x + fmaxf(v1 + a2.y, 0.f) * wf.y
               + fmaxf(v2 + a2.z, 0.f) * wf.z + fmaxf(v3 + a2.w, 0.f) * wf.w;
        }
        for (int off = 32; off > 0; off >>= 1) s += __shfl_down(s, off);
        if (lane == 0) e[(size_t)b * NP + p0 + p] = s + b_fa[0];
    }
}

// ---------------- k_awe: softmax + awe (bf16 enc) + gate + xh (grid 8 x 32) ----------------
__global__ __launch_bounds__(256) void k_awe(
    const unsigned short* __restrict__ encB, const int* __restrict__ dlens,
    const int* __restrict__ sind, const int* __restrict__ caps, const float* __restrict__ emb_W,
    const float* __restrict__ e, const float* __restrict__ attg,
    float* __restrict__ xh, float* __restrict__ out_alpha, int t)
{
    __shared__ float es[256];
    __shared__ float red[256];
    int kc = blockIdx.x, b = blockIdx.y, tid = threadIdx.x;
    float ev = -1e30f;
    if (tid < NP) { float v = e[(size_t)b * NP + tid]; es[tid] = v; ev = v; }
    red[tid] = ev; __syncthreads();
    for (int s2 = 128; s2 > 0; s2 >>= 1) { if (tid < s2) red[tid] = fmaxf(red[tid], red[tid + s2]); __syncthreads(); }
    float m = red[0]; __syncthreads();
    float xe = (tid < NP) ? expf(es[tid] - m) : 0.f;
    red[tid] = xe; __syncthreads();
    for (int s2 = 128; s2 > 0; s2 >>= 1) { if (tid < s2) red[tid] += red[tid + s2]; __syncthreads(); }
    float inv = 1.0f / red[0];
    __syncthreads();
    es[tid] = xe * inv;
    __syncthreads();

    int k = kc * 256 + tid;
    const unsigned short* ec = encB + (size_t)b * NP * NE + k;
    float s0 = 0.f, s1 = 0.f, s2v = 0.f, s3 = 0.f;
    #pragma unroll 4
    for (int p = 0; p < NP; p += 4) {
        s0 += es[p + 0] * b2f(ec[(size_t)(p + 0) * NE]);
        s1 += es[p + 1] * b2f(ec[(size_t)(p + 1) * NE]);
        s2v += es[p + 2] * b2f(ec[(size_t)(p + 2) * NE]);
        s3 += es[p + 3] * b2f(ec[(size_t)(p + 3) * NE]);
    }
    float awe = (s0 + s1) + (s2v + s3);
    float gp = attg[(size_t)b * 2560 + 512 + k];      // includes b_fb
    float gate = 1.f / (1.f + expf(-gp));
    xh[(size_t)b * 3072 + 512 + k] = gate * awe;
    if (kc == 0) {
        bool live = (t < dlens[b]);
        if (tid < NP) out_alpha[((size_t)b * NT + t) * NP + tid] = live ? es[tid] : 0.f;
        const float* er = emb_W + (size_t)caps[sind[b] * NL + t] * ND;
        xh[(size_t)b * 3072 + tid] = er[tid];
        xh[(size_t)b * 3072 + 256 + tid] = er[256 + tid];
    }
}

// ---------------- k_gates: gates GEMM partials (128 blocks: 32 ntiles x 4 ksplit of 768) ----------------
__global__ __launch_bounds__(256) void k_gates(
    const float* __restrict__ xh, const float* __restrict__ W_ih, const float* __restrict__ W_hh,
    float* __restrict__ gpart)
{
    __shared__ float smem[3200];
    int blk = blockIdx.x, tid = threadIdx.x;
    int nt = blk & 31, ks = blk >> 5;
    float* As = smem;
    float (*Ws)[33] = (float(*)[33])(smem + 1024);
    int n0 = nt * 64;
    int lb = tid / 8, lkq = tid % 8;
    int b4 = (tid / 32) * 4, nl = (tid % 32) * 2;
    float acc[4][2] = {};
    for (int kt = ks * 768; kt < ks * 768 + 768; kt += 32) {
        float4 a4 = *reinterpret_cast<const float4*>(xh + (size_t)lb * 3072 + kt + lkq * 4);
        As[(lkq * 4 + 0) * 32 + lb] = a4.x; As[(lkq * 4 + 1) * 32 + lb] = a4.y;
        As[(lkq * 4 + 2) * 32 + lb] = a4.z; As[(lkq * 4 + 3) * 32 + lb] = a4.w;
        #pragma unroll
        for (int r = 0; r < 2; ++r) {
            int s = tid + r * 256;
            int n_l = s / 8, kq = s % 8;
            int ng = n0 + n_l;
            int kk = kt + kq * 4;
            const float* wrow = (kk < 2560) ? (W_ih + (size_t)ng * 2560 + kk)
                                            : (W_hh + (size_t)ng * 512 + (kk - 2560));
            float4 w4 = *reinterpret_cast<const float4*>(wrow);
            Ws[n_l][kq * 4 + 0] = w4.x; Ws[n_l][kq * 4 + 1] = w4.y;
            Ws[n_l][kq * 4 + 2] = w4.z; Ws[n_l][kq * 4 + 3] = w4.w;
        }
        __syncthreads();
        #pragma unroll
        for (int k = 0; k < 32; ++k) {
            float4 av = *reinterpret_cast<const float4*>(&As[k * 32 + b4]);
            float w0 = Ws[nl][k], w1 = Ws[nl + 1][k];
            acc[0][0] += av.x * w0; acc[0][1] += av.x * w1;
            acc[1][0] += av.y * w0; acc[1][1] += av.y * w1;
            acc[2][0] += av.z * w0; acc[2][1] += av.z * w1;
            acc[3][0] += av.w * w0; acc[3][1] += av.w * w1;
        }
        __syncthreads();
    }
    float* Cp = gpart + (size_t)ks * NB * 2048;
    #pragma unroll
    for (int j = 0; j < 2; ++j)
        #pragma unroll
        for (int i = 0; i < 4; ++i)
            Cp[(size_t)(b4 + i) * 2048 + n0 + nl + j] = acc[i][j];
}

// ---------------- k_cell: reduce partials + LSTM cell; hseq stored bf16 ----------------
__global__ __launch_bounds__(256) void k_cell(
    const float* __restrict__ gpart, const int* __restrict__ dlens,
    const float* __restrict__ b_ih, const float* __restrict__ b_hh,
    float* __restrict__ hc, unsigned short* __restrict__ hseqB, float* __restrict__ xh, int t)
{
    int b = blockIdx.x;
    for (int d = threadIdx.x; d < ND; d += 256) {
        float g0 = b_ih[d] + b_hh[d];
        float g1 = b_ih[512 + d] + b_hh[512 + d];
        float g2 = b_ih[1024 + d] + b_hh[1024 + d];
        float g3 = b_ih[1536 + d] + b_hh[1536 + d];
        #pragma unroll
        for (int ks = 0; ks < 4; ++ks) {
            const float* gp = gpart + ((size_t)ks * NB + b) * 2048;
            g0 += gp[d]; g1 += gp[512 + d]; g2 += gp[1024 + d]; g3 += gp[1536 + d];
        }
        float ig = 1.f / (1.f + expf(-g0));
        float fg = 1.f / (1.f + expf(-g1));
        float gt = tanhf(g2);
        float og = 1.f / (1.f + expf(-g3));
        float c_old = hc[(size_t)b * 1024 + 512 + d];
        float c_new = fg * c_old + ig * gt;
        float h_new = og * tanhf(c_new);
        hseqB[((size_t)t * NB + b) * ND + d] = f2b(h_new);
        if (t < dlens[b]) {
            hc[(size_t)b * 1024 + d] = h_new;
            hc[(size_t)b * 1024 + 512 + d] = c_new;
            xh[(size_t)b * 3072 + 2560 + d] = h_new;
        }
    }
}

// ---------------- launcher ----------------
extern "C" void kernel_launch(void* const* d_in, const int* in_sizes, int n_in,
                              void* d_out, int out_size, void* d_ws, size_t ws_size,
                              hipStream_t stream)
{
    const float* enc   = (const float*)d_in[0];
    const int*   caps  = (const int*)d_in[1];
    const int*   clens = (const int*)d_in[2];
    const float* emb_W = (const float*)d_in[3];
    const float* W_ea  = (const float*)d_in[4];
    const float* b_ea  = (const float*)d_in[5];
    const float* W_da  = (const float*)d_in[6];
    const float* b_da  = (const float*)d_in[7];
    const float* w_fa  = (const float*)d_in[8];
    const float* b_fa  = (const float*)d_in[9];
    const float* W_ih  = (const float*)d_in[10];
    const float* b_ih  = (const float*)d_in[11];
    const float* W_hh  = (const float*)d_in[12];
    const float* b_hh  = (const float*)d_in[13];
    const float* W_h0  = (const float*)d_in[14];
    const float* b_h0  = (const float*)d_in[15];
    const float* W_c0  = (const float*)d_in[16];
    const float* b_c0  = (const float*)d_in[17];
    const float* W_fb  = (const float*)d_in[18];
    const float* b_fb  = (const float*)d_in[19];
    const float* W_fc  = (const float*)d_in[20];
    const float* b_fc  = (const float*)d_in[21];

    float* out = (float*)d_out;
    float* out_alpha = out + (size_t)NB * NT * NV;

    int* iws    = (int*)d_ws;
    int* sind   = iws;
    int* dlens  = iws + 32;
    int* rowmap = iws + 64;
    int* mpad   = iws + 704;
    float* base = (float*)d_ws + 1024;
    float* mean_enc = base;                         // 65536
    float* hc    = mean_enc + NB * NE;              // 32768
    float* attg  = hc + NB * 1024;                  // 81920
    float* xh    = attg + NB * 2560;                // 98304
    float* e     = xh + NB * 3072;                  // 6272
    float* gpart = e + NB * NP;                     // 262144 (spart at setup)
    unsigned short* att1B = (unsigned short*)(gpart + 262144);          // 6272*512 bf16
    unsigned short* hseqB = att1B + (size_t)NB * NP * ND;               // 640*512 bf16
    unsigned short* encB  = hseqB + (size_t)NT * NB * ND;               // 32*196*2048 bf16

    k_sort<<<1, 64, 0, stream>>>(clens, sind, dlens, rowmap, mpad);
    k_zero<<<NB * NT, 256, 0, stream>>>(dlens, out);
    k_conv_enc<<<dim3(NB * NP * NE / 2048), 256, 0, stream>>>(enc, sind, encB);
    k_mean<<<dim3(NE / 256, NB), 256, 0, stream>>>(enc, sind, mean_enc);
    gemm_skinny_split<<<dim3(16, 8), 256, 0, stream>>>(mean_enc, W_h0, W_c0, gpart);
    k_hc0<<<dim3(NB), 256, 0, stream>>>(gpart, b_h0, b_c0, hc, xh);
    gemm_att1_mfma<<<dim3(832), 256, 0, stream>>>(encB, W_ea, b_ea, att1B);

    for (int t = 0; t < NT; ++t) {
        k_attg<<<dim3(40), 256, 0, stream>>>(hc, W_da, W_fb, b_da, b_fb, attg);
        k_e<<<dim3(7, NB), 256, 0, stream>>>(att1B, attg, w_fa, b_fa, e);
        k_awe<<<dim3(8, NB), 256, 0, stream>>>(encB, dlens, sind, caps, emb_W,
                                               e, attg, xh, out_alpha, t);
        k_gates<<<dim3(128), 256, 0, stream>>>(xh, W_ih, W_hh, gpart);
        k_cell<<<dim3(NB), 256, 0, stream>>>(gpart, dlens, b_ih, b_hh, hc, hseqB, xh, t);
    }

    gemm_preds_mfma<<<dim3(2560), 256, 0, stream>>>(hseqB, W_fc, b_fc, out, rowmap, mpad);
}

// Round 17
// 1579.153 us; speedup vs baseline: 1.3542x; 1.1430x over previous
//
#include <hip/hip_runtime.h>
#include <hip/hip_bf16.h>
#include <cstddef>

#define NB 32      // batch
#define NP 196     // pixels
#define NE 2048    // encoder dim
#define ND 512     // decoder/att/emb dim
#define NV 32000   // vocab
#define NL 21
#define NT 20      // decode steps

typedef __attribute__((ext_vector_type(8))) short short8;   // 8 bf16 (4 VGPRs)
typedef __attribute__((ext_vector_type(4))) float f32x4;

__device__ __forceinline__ unsigned short f2b(float f) {
    __hip_bfloat16 h = __float2bfloat16(f);      // RNE
    return *reinterpret_cast<unsigned short*>(&h);
}
__device__ __forceinline__ float b2f(unsigned short u) {
    union { unsigned int i; float f; } v; v.i = (unsigned)u << 16; return v.f;
}
__device__ __forceinline__ float b2f_lo(unsigned int u) {
    union { unsigned int i; float f; } v; v.i = u << 16; return v.f;
}
__device__ __forceinline__ float b2f_hi(unsigned int u) {
    union { unsigned int i; float f; } v; v.i = u & 0xffff0000u; return v.f;
}

// ---------------- setup ----------------

__global__ void k_sort(const int* __restrict__ lens, int* __restrict__ sind, int* __restrict__ dlens,
                       int* __restrict__ rowmap, int* __restrict__ mpad)
{
    int i = threadIdx.x;
    if (i < NB) {
        int li = lens[i];
        int r = 0;
        for (int j = 0; j < NB; ++j) {
            int lj = lens[j];
            if (lj > li || (lj == li && j < i)) ++r;
        }
        sind[r] = i;
        dlens[r] = li - 1;
    }
    __syncthreads();
    if (i == 0) {
        int c = 0;
        for (int t = 0; t < NT; ++t)
            for (int b = 0; b < NB; ++b)
                if (t < dlens[b]) rowmap[c++] = t * NB + b;
        int pad = (c + 63) & ~63;
        for (int r = c; r < pad; ++r) rowmap[r] = -1;
        mpad[0] = pad;
    }
}

// enc (sorted) -> bf16 copy (grid 6272) — consumed by k_awe only
__global__ __launch_bounds__(256) void k_conv_enc(
    const float* __restrict__ enc, const int* __restrict__ sind,
    unsigned short* __restrict__ encB)
{
    int idx = (blockIdx.x * 256 + threadIdx.x) * 8;
    int b = idx / (NP * NE), rem = idx - b * (NP * NE);
    const float* src = enc + (size_t)sind[b] * NP * NE + rem;
    float4 a = *reinterpret_cast<const float4*>(src);
    float4 c = *reinterpret_cast<const float4*>(src + 4);
    uint4 o;
    o.x = f2b(a.x) | ((unsigned)f2b(a.y) << 16);
    o.y = f2b(a.z) | ((unsigned)f2b(a.w) << 16);
    o.z = f2b(c.x) | ((unsigned)f2b(c.y) << 16);
    o.w = f2b(c.z) | ((unsigned)f2b(c.w) << 16);
    *reinterpret_cast<uint4*>(encB + idx) = o;
}

// embS[t][b][512] = emb_W[caps[sind[b]][t]]   (grid (NT, NB))
__global__ __launch_bounds__(256) void k_emb(
    const int* __restrict__ caps, const int* __restrict__ sind,
    const float* __restrict__ emb_W, float* __restrict__ embS)
{
    int t = blockIdx.x, b = blockIdx.y;
    const float* src = emb_W + (size_t)caps[sind[b] * NL + t] * ND;
    float* dst = embS + ((size_t)t * NB + b) * ND;
    int i = threadIdx.x * 2;
    *reinterpret_cast<float2*>(dst + i) = *reinterpret_cast<const float2*>(src + i);
}

__global__ __launch_bounds__(256) void k_mean(const float* __restrict__ enc, const int* __restrict__ sind,
                                              float* __restrict__ mean_enc)
{
    int b = blockIdx.y;
    int k = blockIdx.x * 256 + threadIdx.x;
    const float* e = enc + (size_t)sind[b] * NP * NE + k;
    float s0 = 0.f, s1 = 0.f, s2 = 0.f, s3 = 0.f;
    for (int p = 0; p < NP; p += 4) {
        s0 += e[(size_t)(p + 0) * NE];
        s1 += e[(size_t)(p + 1) * NE];
        s2 += e[(size_t)(p + 2) * NE];
        s3 += e[(size_t)(p + 3) * NE];
    }
    mean_enc[(size_t)b * NE + k] = (s0 + s1 + s2 + s3) * (1.0f / NP);
}

__global__ __launch_bounds__(256) void k_zero(const int* __restrict__ dlens, float* __restrict__ out)
{
    int b = blockIdx.x / NT, t = blockIdx.x % NT;
    if (t < dlens[b]) return;
    float4 z = {0.f, 0.f, 0.f, 0.f};
    float4* row = (float4*)(out + ((size_t)b * NT + t) * NV);
    for (int i = threadIdx.x; i < NV / 4; i += 256) row[i] = z;
}

// ---------------- shared tile body: C_part[32][64] = A[32][K] @ W^T (uniform W) ----------------
__device__ __forceinline__ void tile_body_uniW(
    const float* __restrict__ A, int lda, const float* __restrict__ W, int wstride,
    int n0, int kbeg, int kend, float* As, float (*Ws)[33], float acc[4][2],
    int tid)
{
    int lb = tid / 8, lkq = tid % 8;
    int b4 = (tid / 32) * 4, nl = (tid % 32) * 2;
    for (int kt = kbeg; kt < kend; kt += 32) {
        float4 a4 = *reinterpret_cast<const float4*>(A + (size_t)lb * lda + kt + lkq * 4);
        As[(lkq * 4 + 0) * 32 + lb] = a4.x; As[(lkq * 4 + 1) * 32 + lb] = a4.y;
        As[(lkq * 4 + 2) * 32 + lb] = a4.z; As[(lkq * 4 + 3) * 32 + lb] = a4.w;
        #pragma unroll
        for (int r = 0; r < 2; ++r) {
            int s = tid + r * 256;
            int n_l = s / 8, kq = s % 8;
            float4 w4 = *reinterpret_cast<const float4*>(W + (size_t)(n0 + n_l) * wstride + kt + kq * 4);
            Ws[n_l][kq * 4 + 0] = w4.x; Ws[n_l][kq * 4 + 1] = w4.y;
            Ws[n_l][kq * 4 + 2] = w4.z; Ws[n_l][kq * 4 + 3] = w4.w;
        }
        __syncthreads();
        #pragma unroll
        for (int k = 0; k < 32; ++k) {
            float4 av = *reinterpret_cast<const float4*>(&As[k * 32 + b4]);
            float w0 = Ws[nl][k], w1 = Ws[nl + 1][k];
            acc[0][0] += av.x * w0; acc[0][1] += av.x * w1;
            acc[1][0] += av.y * w0; acc[1][1] += av.y * w1;
            acc[2][0] += av.z * w0; acc[2][1] += av.z * w1;
            acc[3][0] += av.w * w0; acc[3][1] += av.w * w1;
        }
        __syncthreads();
    }
}

// ---------------- h0/c0 skinny GEMM, split-K=8 (grid 16 x 8) -> partials in spart ----------------
__global__ __launch_bounds__(256) void gemm_skinny_split(
    const float* __restrict__ A0, const float* __restrict__ W0a, const float* __restrict__ W0b,
    float* __restrict__ spart)
{
    __shared__ float As[1024];
    __shared__ float Ws[64][33];
    int n0 = blockIdx.x * 64;
    int ks = blockIdx.y;
    int tid = threadIdx.x;
    int lb = tid / 8, lkq = tid % 8;
    int b4 = (tid / 32) * 4, nl = (tid % 32) * 2;
    float acc[4][2] = {};
    for (int kt = ks * 256; kt < ks * 256 + 256; kt += 32) {
        float4 a4 = *reinterpret_cast<const float4*>(A0 + (size_t)lb * NE + kt + lkq * 4);
        As[(lkq * 4 + 0) * 32 + lb] = a4.x; As[(lkq * 4 + 1) * 32 + lb] = a4.y;
        As[(lkq * 4 + 2) * 32 + lb] = a4.z; As[(lkq * 4 + 3) * 32 + lb] = a4.w;
        #pragma unroll
        for (int r = 0; r < 2; ++r) {
            int s = tid + r * 256;
            int n_l = s / 8, kq = s % 8;
            int ng = n0 + n_l;
            const float* wrow = (ng < 512) ? (W0a + (size_t)ng * NE)
                                           : (W0b + (size_t)(ng - 512) * NE);
            float4 w4 = *reinterpret_cast<const float4*>(wrow + kt + kq * 4);
            Ws[n_l][kq * 4 + 0] = w4.x; Ws[n_l][kq * 4 + 1] = w4.y;
            Ws[n_l][kq * 4 + 2] = w4.z; Ws[n_l][kq * 4 + 3] = w4.w;
        }
        __syncthreads();
        #pragma unroll
        for (int k = 0; k < 32; ++k) {
            float4 av = *reinterpret_cast<const float4*>(&As[k * 32 + b4]);
            float w0 = Ws[nl][k], w1 = Ws[nl + 1][k];
            acc[0][0] += av.x * w0; acc[0][1] += av.x * w1;
            acc[1][0] += av.y * w0; acc[1][1] += av.y * w1;
            acc[2][0] += av.z * w0; acc[2][1] += av.z * w1;
            acc[3][0] += av.w * w0; acc[3][1] += av.w * w1;
        }
        __syncthreads();
    }
    float* Cp = spart + (size_t)ks * NB * 1024;
    #pragma unroll
    for (int j = 0; j < 2; ++j)
        #pragma unroll
        for (int i = 0; i < 4; ++i)
            Cp[(size_t)(b4 + i) * 1024 + n0 + nl + j] = acc[i][j];
}

// combine partials + bias -> hc (grid NB)
__global__ __launch_bounds__(256) void k_hc0(
    const float* __restrict__ spart, const float* __restrict__ ba, const float* __restrict__ bb,
    float* __restrict__ hc)
{
    int b = blockIdx.x;
    for (int ng = threadIdx.x; ng < 1024; ng += 256) {
        float s = (ng < 512) ? ba[ng] : bb[ng - 512];
        #pragma unroll
        for (int ks = 0; ks < 8; ++ks)
            s += spart[(size_t)ks * NB * 1024 + (size_t)b * 1024 + ng];
        hc[(size_t)b * 1024 + ng] = s;
    }
}

// ---------------- att1 GEMM (bf16 MFMA), fp32 A with inline cvt, XCD-swizzled (R11-proven) ----------------
__global__ __launch_bounds__(256) void gemm_att1_mfma(
    const float* __restrict__ enc, const float* __restrict__ W_ea,
    const float* __restrict__ bias, unsigned short* __restrict__ att1B,
    const int* __restrict__ sind)
{
    int fid = blockIdx.x;
    int c = fid & 7, x = (fid >> 3) & 7, pg = fid >> 6;
    int p = pg * 8 + c;
    if (p >= 98) return;
    int bm0 = p * 64, bn0 = x * 64;
    __shared__ unsigned short As[64][40];
    __shared__ unsigned short Bs[64][40];
    int tid = threadIdx.x;
    int w = tid >> 6, lane = tid & 63;
    int srow = tid >> 2, schunk = (tid & 3) * 8;
    int mg = bm0 + srow;
    int bidx = mg / NP, pp = mg - bidx * NP;
    const float* arow = enc + ((size_t)sind[bidx] * NP + pp) * NE + schunk;
    const float* brow = W_ea + (size_t)(bn0 + srow) * NE + schunk;
    int frow = lane & 15, fk = (lane >> 4) * 8;
    f32x4 acc[4] = {};
    for (int kt = 0; kt < NE; kt += 32) {
        float4 a0 = *reinterpret_cast<const float4*>(arow + kt);
        float4 a1 = *reinterpret_cast<const float4*>(arow + kt + 4);
        float4 b0 = *reinterpret_cast<const float4*>(brow + kt);
        float4 b1 = *reinterpret_cast<const float4*>(brow + kt + 4);
        uint4 av, bv;
        av.x = f2b(a0.x) | ((unsigned)f2b(a0.y) << 16);
        av.y = f2b(a0.z) | ((unsigned)f2b(a0.w) << 16);
        av.z = f2b(a1.x) | ((unsigned)f2b(a1.y) << 16);
        av.w = f2b(a1.z) | ((unsigned)f2b(a1.w) << 16);
        bv.x = f2b(b0.x) | ((unsigned)f2b(b0.y) << 16);
        bv.y = f2b(b0.z) | ((unsigned)f2b(b0.w) << 16);
        bv.z = f2b(b1.x) | ((unsigned)f2b(b1.y) << 16);
        bv.w = f2b(b1.z) | ((unsigned)f2b(b1.w) << 16);
        *reinterpret_cast<uint4*>(&As[srow][schunk]) = av;
        *reinterpret_cast<uint4*>(&Bs[srow][schunk]) = bv;
        __syncthreads();
        short8 af = *reinterpret_cast<const short8*>(&As[w * 16 + frow][fk]);
        #pragma unroll
        for (int n = 0; n < 4; ++n) {
            short8 bf = *reinterpret_cast<const short8*>(&Bs[n * 16 + frow][fk]);
            acc[n] = __builtin_amdgcn_mfma_f32_16x16x32_bf16(af, bf, acc[n], 0, 0, 0);
        }
        __syncthreads();
    }
    int crow = bm0 + w * 16 + (lane >> 4) * 4;
    int ccol0 = lane & 15;
    #pragma unroll
    for (int n = 0; n < 4; ++n) {
        int col = bn0 + n * 16 + ccol0;
        float bb2 = bias[col];
        #pragma unroll
        for (int i = 0; i < 4; ++i)
            att1B[(size_t)(crow + i) * ND + col] = f2b(acc[n][i] + bb2);
    }
}

// ---------------- preds GEMM (bf16 MFMA), XCD-swizzled ----------------
__global__ __launch_bounds__(256) void gemm_preds_mfma(
    const unsigned short* __restrict__ hseqB, const float* __restrict__ W_fc,
    const float* __restrict__ bias, float* __restrict__ out,
    const int* __restrict__ rowmap, const int* __restrict__ mpad)
{
    int fid = blockIdx.x;
    int c = fid & 7;
    int rem = fid >> 3;
    int m = rem % 10, g = rem / 10;
    int n = g * 8 + c;
    if (n >= 250) return;
    int bm0 = m * 64;
    if (bm0 >= mpad[0]) return;
    int bn0 = n * 128;
    __shared__ unsigned short As[64][40];
    __shared__ unsigned short Bs[128][40];
    int tid = threadIdx.x;
    int w = tid >> 6, lane = tid & 63;
    int srow = tid >> 2, schunk = (tid & 3) * 8;
    int rid = rowmap[bm0 + srow];
    const unsigned short* aptr = hseqB + (size_t)(rid < 0 ? 0 : rid) * ND + schunk;
    const float* bptr0 = W_fc + (size_t)(bn0 + srow) * ND + schunk;
    const float* bptr1 = W_fc + (size_t)(bn0 + 64 + srow) * ND + schunk;
    int frow = lane & 15, fk = (lane >> 4) * 8;
    f32x4 acc[8] = {};
    for (int kt = 0; kt < ND; kt += 32) {
        uint4 av = *reinterpret_cast<const uint4*>(aptr + kt);
        float4 c0 = *reinterpret_cast<const float4*>(bptr0 + kt);
        float4 c1 = *reinterpret_cast<const float4*>(bptr0 + kt + 4);
        float4 d0 = *reinterpret_cast<const float4*>(bptr1 + kt);
        float4 d1 = *reinterpret_cast<const float4*>(bptr1 + kt + 4);
        uint4 bv0, bv1;
        bv0.x = f2b(c0.x) | ((unsigned)f2b(c0.y) << 16);
        bv0.y = f2b(c0.z) | ((unsigned)f2b(c0.w) << 16);
        bv0.z = f2b(c1.x) | ((unsigned)f2b(c1.y) << 16);
        bv0.w = f2b(c1.z) | ((unsigned)f2b(c1.w) << 16);
        bv1.x = f2b(d0.x) | ((unsigned)f2b(d0.y) << 16);
        bv1.y = f2b(d0.z) | ((unsigned)f2b(d0.w) << 16);
        bv1.z = f2b(d1.x) | ((unsigned)f2b(d1.y) << 16);
        bv1.w = f2b(d1.z) | ((unsigned)f2b(d1.w) << 16);
        *reinterpret_cast<uint4*>(&As[srow][schunk]) = av;
        *reinterpret_cast<uint4*>(&Bs[srow][schunk]) = bv0;
        *reinterpret_cast<uint4*>(&Bs[64 + srow][schunk]) = bv1;
        __syncthreads();
        short8 af = *reinterpret_cast<const short8*>(&As[w * 16 + frow][fk]);
        #pragma unroll
        for (int nn = 0; nn < 8; ++nn) {
            short8 bf = *reinterpret_cast<const short8*>(&Bs[nn * 16 + frow][fk]);
            acc[nn] = __builtin_amdgcn_mfma_f32_16x16x32_bf16(af, bf, acc[nn], 0, 0, 0);
        }
        __syncthreads();
    }
    int rl0 = w * 16 + (lane >> 4) * 4;
    int ccol0 = lane & 15;
    #pragma unroll
    for (int i = 0; i < 4; ++i) {
        int rm = rowmap[bm0 + rl0 + i];
        if (rm < 0) continue;
        int t = rm / NB, b = rm % NB;
        float* orow = out + ((size_t)b * NT + t) * NV;
        #pragma unroll
        for (int nn = 0; nn < 8; ++nn) {
            int col = bn0 + nn * 16 + ccol0;
            orow[col] = acc[nn][i] + bias[col];
        }
    }
}

// ---------------- k_phase1: attg (blocks 0..39) + eh gate-partials (blocks 40..103) ----------------
// attg[32][2560] = h @ [W_da;W_fb]^T + bias
// gpart slice4 = embS[t] @ W_ih[:,0:512]^T ; slice5 = h @ W_hh^T
__global__ __launch_bounds__(256) void k_phase1(
    const float* __restrict__ hc, const float* __restrict__ W_da, const float* __restrict__ W_fb,
    const float* __restrict__ b_da, const float* __restrict__ b_fb,
    const float* __restrict__ embS, const float* __restrict__ W_ih, const float* __restrict__ W_hh,
    float* __restrict__ attg, float* __restrict__ gpart, int t)
{
    __shared__ float As[1024];
    __shared__ float Ws[64][33];
    int blk = blockIdx.x, tid = threadIdx.x;
    int b4 = (tid / 32) * 4, nl = (tid % 32) * 2;
    float acc[4][2] = {};
    if (blk < 40) {
        int n0 = blk * 64;
        int lb = tid / 8, lkq = tid % 8;
        for (int kt = 0; kt < 512; kt += 32) {
            float4 a4 = *reinterpret_cast<const float4*>(hc + (size_t)lb * 1024 + kt + lkq * 4);
            As[(lkq * 4 + 0) * 32 + lb] = a4.x; As[(lkq * 4 + 1) * 32 + lb] = a4.y;
            As[(lkq * 4 + 2) * 32 + lb] = a4.z; As[(lkq * 4 + 3) * 32 + lb] = a4.w;
            #pragma unroll
            for (int r = 0; r < 2; ++r) {
                int s = tid + r * 256;
                int n_l = s / 8, kq = s % 8;
                int ng = n0 + n_l;
                const float* wrow = (ng < 512) ? (W_da + (size_t)ng * 512)
                                               : (W_fb + (size_t)(ng - 512) * 512);
                float4 w4 = *reinterpret_cast<const float4*>(wrow + kt + kq * 4);
                Ws[n_l][kq * 4 + 0] = w4.x; Ws[n_l][kq * 4 + 1] = w4.y;
                Ws[n_l][kq * 4 + 2] = w4.z; Ws[n_l][kq * 4 + 3] = w4.w;
            }
            __syncthreads();
            #pragma unroll
            for (int k = 0; k < 32; ++k) {
                float4 av = *reinterpret_cast<const float4*>(&As[k * 32 + b4]);
                float w0 = Ws[nl][k], w1 = Ws[nl + 1][k];
                acc[0][0] += av.x * w0; acc[0][1] += av.x * w1;
                acc[1][0] += av.y * w0; acc[1][1] += av.y * w1;
                acc[2][0] += av.z * w0; acc[2][1] += av.z * w1;
                acc[3][0] += av.w * w0; acc[3][1] += av.w * w1;
            }
            __syncthreads();
        }
        #pragma unroll
        for (int j = 0; j < 2; ++j) {
            int ng = n0 + nl + j;
            float bias = (ng < 512) ? b_da[ng] : b_fb[ng - 512];
            #pragma unroll
            for (int i = 0; i < 4; ++i)
                attg[(size_t)(b4 + i) * 2560 + ng] = acc[i][j] + bias;
        }
    } else if (blk < 72) {
        // emb-columns: gpart slice4 = embS[t] @ W_ih[:,0:512]^T
        int nt = blk - 40, n0 = nt * 64;
        tile_body_uniW(embS + (size_t)t * NB * ND, ND, W_ih, 2560, n0, 0, 512, As, Ws, acc, tid);
        float* Cp = gpart + (size_t)4 * NB * 2048;
        #pragma unroll
        for (int j = 0; j < 2; ++j)
            #pragma unroll
            for (int i = 0; i < 4; ++i)
                Cp[(size_t)(b4 + i) * 2048 + n0 + nl + j] = acc[i][j];
    } else {
        // h: gpart slice5 = h @ W_hh^T
        int nt = blk - 72, n0 = nt * 64;
        tile_body_uniW(hc, 1024, W_hh, 512, n0, 0, 512, As, Ws, acc, tid);
        float* Cp = gpart + (size_t)5 * NB * 2048;
        #pragma unroll
        for (int j = 0; j < 2; ++j)
            #pragma unroll
            for (int i = 0; i < 4; ++i)
                Cp[(size_t)(b4 + i) * 2048 + n0 + nl + j] = acc[i][j];
    }
}

// ---------------- k_e: e scores from bf16 att1 (grid 7 x 32) ----------------
__global__ __launch_bounds__(256) void k_e(
    const unsigned short* __restrict__ att1B, const float* __restrict__ attg,
    const float* __restrict__ w_fa, const float* __restrict__ b_fa,
    float* __restrict__ e)
{
    __shared__ float att2s[ND];
    __shared__ float wfas[ND];
    int b = blockIdx.y, tid = threadIdx.x;
    const float* ag = attg + (size_t)b * 2560;
    for (int d = tid; d < ND; d += 256) { att2s[d] = ag[d]; wfas[d] = w_fa[d]; }
    __syncthreads();
    int w = tid >> 6, lane = tid & 63;
    int p0 = blockIdx.x * 28;
    const unsigned short* a1 = att1B + ((size_t)b * NP + p0) * ND;
    #pragma unroll
    for (int i = 0; i < 7; ++i) {
        int p = w + 4 * i;
        const unsigned short* row = a1 + (size_t)p * ND;
        float s = 0.f;
        #pragma unroll
        for (int j = 0; j < 2; ++j) {
            int d = j * 256 + lane * 4;
            uint2 u = *reinterpret_cast<const uint2*>(row + d);   // 4 bf16
            float v0 = b2f_lo(u.x), v1 = b2f_hi(u.x);
            float v2 = b2f_lo(u.y), v3 = b2f_hi(u.y);
            float4 a2 = *reinterpret_cast<const float4*>(&att2s[d]);
            float4 wf = *reinterpret_cast<const float4*>(&wfas[d]);
            s += fmaxf(v0 + a2.x, 0.f) * wf.x + fmaxf(v1 + a2.y, 0.f) * wf.y
               + fmaxf(v2 + a2.z, 0.f) * wf.z + fmaxf(v3 + a2.w, 0.f) * wf.w;
        }
        for (int off = 32; off > 0; off >>= 1) s += __shfl_down(s, off);
        if (lane == 0) e[(size_t)b * NP + p0 + p] = s + b_fa[0];
    }
}

// ---------------- k_awe: softmax + awe (bf16 enc) + gate -> xh gawe; alpha (grid 8 x 32) ----------------
__global__ __launch_bounds__(256) void k_awe(
    const unsigned short* __restrict__ encB, const int* __restrict__ dlens,
    const float* __restrict__ e, const float* __restrict__ attg,
    float* __restrict__ xh, float* __restrict__ out_alpha, int t)
{
    __shared__ float es[256];
    __shared__ float red[256];
    int kc = blockIdx.x, b = blockIdx.y, tid = threadIdx.x;
    float ev = -1e30f;
    if (tid < NP) { float v = e[(size_t)b * NP + tid]; es[tid] = v; ev = v; }
    red[tid] = ev; __syncthreads();
    for (int s2 = 128; s2 > 0; s2 >>= 1) { if (tid < s2) red[tid] = fmaxf(red[tid], red[tid + s2]); __syncthreads(); }
    float m = red[0]; __syncthreads();
    float xe = (tid < NP) ? expf(es[tid] - m) : 0.f;
    red[tid] = xe; __syncthreads();
    for (int s2 = 128; s2 > 0; s2 >>= 1) { if (tid < s2) red[tid] += red[tid + s2]; __syncthreads(); }
    float inv = 1.0f / red[0];
    __syncthreads();
    es[tid] = xe * inv;
    __syncthreads();

    int k = kc * 256 + tid;
    const unsigned short* ec = encB + (size_t)b * NP * NE + k;
    float s0 = 0.f, s1 = 0.f, s2v = 0.f, s3 = 0.f;
    #pragma unroll 4
    for (int p = 0; p < NP; p += 4) {
        s0 += es[p + 0] * b2f(ec[(size_t)(p + 0) * NE]);
        s1 += es[p + 1] * b2f(ec[(size_t)(p + 1) * NE]);
        s2v += es[p + 2] * b2f(ec[(size_t)(p + 2) * NE]);
        s3 += es[p + 3] * b2f(ec[(size_t)(p + 3) * NE]);
    }
    float awe = (s0 + s1) + (s2v + s3);
    float gp = attg[(size_t)b * 2560 + 512 + k];      // includes b_fb
    float gate = 1.f / (1.f + expf(-gp));
    xh[(size_t)b * 3072 + 512 + k] = gate * awe;
    if (kc == 0 && tid < NP) {
        bool live = (t < dlens[b]);
        out_alpha[((size_t)b * NT + t) * NP + tid] = live ? es[tid] : 0.f;
    }
}

// ---------------- k_gates: gawe-columns GEMM partials (128 blocks: 32 ntiles x 4 ksplit of 512) ----
// gpart slice ks = gawe @ W_ih[:, 512+ks*512 : 512+(ks+1)*512]^T
__global__ __launch_bounds__(256) void k_gates(
    const float* __restrict__ xh, const float* __restrict__ W_ih,
    float* __restrict__ gpart)
{
    __shared__ float As[1024];
    __shared__ float Ws[64][33];
    int blk = blockIdx.x, tid = threadIdx.x;
    int nt = blk & 31, ks = blk >> 5;
    int n0 = nt * 64;
    int b4 = (tid / 32) * 4, nl = (tid % 32) * 2;
    float acc[4][2] = {};
    // A = xh gawe columns (offset 512, lda 3072); W columns offset 512+ks*512
    tile_body_uniW(xh + 512 + (size_t)ks * 512, 3072, W_ih + 512 + (size_t)ks * 512, 2560,
                   n0, 0, 512, As, Ws, acc, tid);
    float* Cp = gpart + (size_t)ks * NB * 2048;
    #pragma unroll
    for (int j = 0; j < 2; ++j)
        #pragma unroll
        for (int i = 0; i < 4; ++i)
            Cp[(size_t)(b4 + i) * 2048 + n0 + nl + j] = acc[i][j];
}

// ---------------- k_cell: reduce 6 partial slices + LSTM cell; hseq stored bf16 ----------------
__global__ __launch_bounds__(256) void k_cell(
    const float* __restrict__ gpart, const int* __restrict__ dlens,
    const float* __restrict__ b_ih, const float* __restrict__ b_hh,
    float* __restrict__ hc, unsigned short* __restrict__ hseqB, int t)
{
    int b = blockIdx.x;
    for (int d = threadIdx.x; d < ND; d += 256) {
        float g0 = b_ih[d] + b_hh[d];
        float g1 = b_ih[512 + d] + b_hh[512 + d];
        float g2 = b_ih[1024 + d] + b_hh[1024 + d];
        float g3 = b_ih[1536 + d] + b_hh[1536 + d];
        #pragma unroll
        for (int ks = 0; ks < 6; ++ks) {
            const float* gp = gpart + ((size_t)ks * NB + b) * 2048;
            g0 += gp[d]; g1 += gp[512 + d]; g2 += gp[1024 + d]; g3 += gp[1536 + d];
        }
        float ig = 1.f / (1.f + expf(-g0));
        float fg = 1.f / (1.f + expf(-g1));
        float gt = tanhf(g2);
        float og = 1.f / (1.f + expf(-g3));
        float c_old = hc[(size_t)b * 1024 + 512 + d];
        float c_new = fg * c_old + ig * gt;
        float h_new = og * tanhf(c_new);
        hseqB[((size_t)t * NB + b) * ND + d] = f2b(h_new);
        if (t < dlens[b]) {
            hc[(size_t)b * 1024 + d] = h_new;
            hc[(size_t)b * 1024 + 512 + d] = c_new;
        }
    }
}

// ---------------- launcher ----------------
extern "C" void kernel_launch(void* const* d_in, const int* in_sizes, int n_in,
                              void* d_out, int out_size, void* d_ws, size_t ws_size,
                              hipStream_t stream)
{
    const float* enc   = (const float*)d_in[0];
    const int*   caps  = (const int*)d_in[1];
    const int*   clens = (const int*)d_in[2];
    const float* emb_W = (const float*)d_in[3];
    const float* W_ea  = (const float*)d_in[4];
    const float* b_ea  = (const float*)d_in[5];
    const float* W_da  = (const float*)d_in[6];
    const float* b_da  = (const float*)d_in[7];
    const float* w_fa  = (const float*)d_in[8];
    const float* b_fa  = (const float*)d_in[9];
    const float* W_ih  = (const float*)d_in[10];
    const float* b_ih  = (const float*)d_in[11];
    const float* W_hh  = (const float*)d_in[12];
    const float* b_hh  = (const float*)d_in[13];
    const float* W_h0  = (const float*)d_in[14];
    const float* b_h0  = (const float*)d_in[15];
    const float* W_c0  = (const float*)d_in[16];
    const float* b_c0  = (const float*)d_in[17];
    const float* W_fb  = (const float*)d_in[18];
    const float* b_fb  = (const float*)d_in[19];
    const float* W_fc  = (const float*)d_in[20];
    const float* b_fc  = (const float*)d_in[21];

    float* out = (float*)d_out;
    float* out_alpha = out + (size_t)NB * NT * NV;

    int* iws    = (int*)d_ws;
    int* sind   = iws;
    int* dlens  = iws + 32;
    int* rowmap = iws + 64;
    int* mpad   = iws + 704;
    float* base = (float*)d_ws + 1024;
    float* mean_enc = base;                         // 65536
    float* hc    = mean_enc + NB * NE;              // 32768
    float* attg  = hc + NB * 1024;                  // 81920
    float* xh    = attg + NB * 2560;                // 98304
    float* e     = xh + NB * 3072;                  // 6272
    float* embS  = e + NB * NP;                     // 20*32*512 = 327680
    float* gpart = embS + (size_t)NT * NB * ND;     // 6*32*2048 = 393216 (spart at setup: 262144 fits)
    unsigned short* att1B = (unsigned short*)(gpart + 6 * NB * 2048);   // 6272*512 bf16
    unsigned short* hseqB = att1B + (size_t)NB * NP * ND;               // 640*512 bf16
    unsigned short* encB  = hseqB + (size_t)NT * NB * ND;               // 32*196*2048 bf16

    k_sort<<<1, 64, 0, stream>>>(clens, sind, dlens, rowmap, mpad);
    k_zero<<<NB * NT, 256, 0, stream>>>(dlens, out);
    k_conv_enc<<<dim3(NB * NP * NE / 2048), 256, 0, stream>>>(enc, sind, encB);
    k_emb<<<dim3(NT, NB), 256, 0, stream>>>(caps, sind, emb_W, embS);
    k_mean<<<dim3(NE / 256, NB), 256, 0, stream>>>(enc, sind, mean_enc);
    gemm_skinny_split<<<dim3(16, 8), 256, 0, stream>>>(mean_enc, W_h0, W_c0, gpart);
    k_hc0<<<dim3(NB), 256, 0, stream>>>(gpart, b_h0, b_c0, hc);
    gemm_att1_mfma<<<dim3(832), 256, 0, stream>>>(enc, W_ea, b_ea, att1B, sind);

    for (int t = 0; t < NT; ++t) {
        k_phase1<<<dim3(104), 256, 0, stream>>>(hc, W_da, W_fb, b_da, b_fb,
                                                embS, W_ih, W_hh, attg, gpart, t);
        k_e<<<dim3(7, NB), 256, 0, stream>>>(att1B, attg, w_fa, b_fa, e);
        k_awe<<<dim3(8, NB), 256, 0, stream>>>(encB, dlens, e, attg, xh, out_alpha, t);
        k_gates<<<dim3(128), 256, 0, stream>>>(xh, W_ih, gpart);
        k_cell<<<dim3(NB), 256, 0, stream>>>(gpart, dlens, b_ih, b_hh, hc, hseqB, t);
    }

    gemm_preds_mfma<<<dim3(2560), 256, 0, stream>>>(hseqB, W_fc, b_fc, out, rowmap, mpad);
}